// Round 7
// baseline (1123.021 us; speedup 1.0000x reference)
//
#include <hip/hip_runtime.h>

#define NN 200000
#define NE 200000
#define HD 256

typedef __attribute__((ext_vector_type(8))) short short8;
typedef __attribute__((ext_vector_type(4))) short short4v;
typedef __attribute__((ext_vector_type(4))) float f32x4;

static __device__ __forceinline__ unsigned short f2bf(float f) {
  unsigned u = __float_as_uint(f);
  u = (u + 0x7FFFu + ((u >> 16) & 1u)) >> 16;
  return (unsigned short)u;
}
static __device__ __forceinline__ float bf2f(unsigned short u) {
  return __uint_as_float(((unsigned)u) << 16);
}
static __device__ __forceinline__ float sigmoidf_(float x) {
  return 1.0f / (1.0f + __expf(-x));
}
static __device__ __forceinline__ float tanhf_(float x) {
  return 2.0f / (1.0f + __expf(-2.0f * x)) - 1.0f;
}
static __device__ __forceinline__ void atomAddF(float* p, float v) {
  __hip_atomic_fetch_add(p, v, __ATOMIC_RELAXED, __HIP_MEMORY_SCOPE_AGENT);
}
static __device__ __forceinline__ int atomAddI(int* p, int v) {
  return __hip_atomic_fetch_add(p, v, __ATOMIC_RELAXED, __HIP_MEMORY_SCOPE_AGENT);
}

// ws layout (bytes)
#define OFF_WFB    0u           // bf16[256*256]
#define OFF_BP     131072u      // packed B fragments: bf16[16*48*64*8] = 786432 B
#define OFF_BPERM  917504u      // f32[768]
#define OFF_ROWPTR 920576u      // int[NN+1]
#define OFF_NEXT   1720832u     // int[NN]
#define OFF_SLOT   2520832u     // int[NE]
#define OFF_PSRC   3320832u     // int[NE]
#define OFF_BSUM   4120832u     // int[256]
#define OFF_ZERO   4121856u     // 1024 B of zeros
#define OFF_FC     4122880u     // bf16[NE*HD]
#define WS_NEED    106522880ull

// --------- prep (fast path): Wfb bf16; B fragment-packed; bias gate-permuted --
// Bp element o = ((kc*48 + tt)*64 + lane)*8 + e  <->  B[row_p][kk] where
//   row_p = tt*16 + (lane&15) (gate-interleaved tile tt), kk = kc*32+(lane>>4)*8+e
__global__ __launch_bounds__(256) void prep_kernel(
    const float* __restrict__ Ufw, const float* __restrict__ Wiou,
    const float* __restrict__ Uiou, const float* __restrict__ biou,
    unsigned short* __restrict__ Wfb, unsigned short* __restrict__ Bp,
    float* __restrict__ bperm) {
  int idx = blockIdx.x * 256 + threadIdx.x;
  if (idx < 65536) {
    Wfb[idx] = f2bf(Ufw[idx]);
  } else if (idx < 458752) {
    int o = idx - 65536;
    int kc = o / 24576;
    int rem = o - kc * 24576;
    int tt = rem / 512;
    int rem2 = rem - tt * 512;
    int ln = rem2 >> 3, e = rem2 & 7;
    int cc = ln & 15, kgp = ln >> 4;
    int kk = kc * 32 + kgp * 8 + e;
    int g = tt % 3, tj = tt / 3;
    int orow = g * 256 + tj * 16 + cc;
    float v = (kk < 256) ? Wiou[orow * 256 + kk] : Uiou[orow * 256 + (kk - 256)];
    Bp[o] = f2bf(v);
  } else if (idx < 459520) {
    int j2 = idx - 458752;
    int T = j2 >> 4, cc = j2 & 15;
    int g = T % 3, tj = T / 3;
    bperm[j2] = biou[g * 256 + tj * 16 + cc];
  }
}

// --------- prep (fallback): plain gate-permuted row-major W/U ---------------
__global__ __launch_bounds__(256) void prep_fb_kernel(
    const float* __restrict__ Ufw, const float* __restrict__ Wiou,
    const float* __restrict__ Uiou, const float* __restrict__ biou,
    unsigned short* __restrict__ Wfb, unsigned short* __restrict__ Wioub,
    unsigned short* __restrict__ Uioub, float* __restrict__ bperm) {
  int idx = blockIdx.x * 256 + threadIdx.x;
  if (idx < 65536) {
    Wfb[idx] = f2bf(Ufw[idx]);
  } else if (idx < 262144) {
    int i2 = idx - 65536;
    int rp = i2 >> 8, k = i2 & 255;
    int T = rp >> 4, cc = rp & 15;
    int g = T % 3, tj = T / 3;
    Wioub[i2] = f2bf(Wiou[(g * 256 + tj * 16 + cc) * 256 + k]);
  } else if (idx < 458752) {
    int i2 = idx - 262144;
    int rp = i2 >> 8, k = i2 & 255;
    int T = rp >> 4, cc = rp & 15;
    int g = T % 3, tj = T / 3;
    Uioub[i2] = f2bf(Uiou[(g * 256 + tj * 16 + cc) * 256 + k]);
  } else if (idx < 459520) {
    int j2 = idx - 458752;
    int T = j2 >> 4, cc = j2 & 15;
    int g = T % 3, tj = T / 3;
    bperm[j2] = biou[g * 256 + tj * 16 + cc];
  }
}

// ---------------- CSR build ----------------
__global__ __launch_bounds__(256) void hist_kernel(const int* __restrict__ edst,
                                                   int* __restrict__ cnt) {
  int e = blockIdx.x * 256 + threadIdx.x;
  if (e < NE) atomAddI(&cnt[edst[e]], 1);
}

__global__ __launch_bounds__(256) void scan_part(const int* __restrict__ cnt,
                                                 int* __restrict__ rp,
                                                 int* __restrict__ bsum) {
  __shared__ int sd[256];
  int t = threadIdx.x;
  int base = blockIdx.x * 1024 + t * 4;
  int v0 = (base + 0 < NN) ? cnt[base + 0] : 0;
  int v1 = (base + 1 < NN) ? cnt[base + 1] : 0;
  int v2 = (base + 2 < NN) ? cnt[base + 2] : 0;
  int v3 = (base + 3 < NN) ? cnt[base + 3] : 0;
  int s = v0 + v1 + v2 + v3;
  sd[t] = s;
  __syncthreads();
  for (int off = 1; off < 256; off <<= 1) {
    int add = (t >= off) ? sd[t - off] : 0;
    __syncthreads();
    sd[t] += add;
    __syncthreads();
  }
  int run = sd[t] - s;  // exclusive
  if (base + 0 < NN) rp[base + 0] = run; run += v0;
  if (base + 1 < NN) rp[base + 1] = run; run += v1;
  if (base + 2 < NN) rp[base + 2] = run; run += v2;
  if (base + 3 < NN) rp[base + 3] = run;
  if (t == 255) bsum[blockIdx.x] = sd[255];
}

__global__ __launch_bounds__(256) void scan_top(int* __restrict__ bsum,
                                                int* __restrict__ rp, int nb) {
  __shared__ int sd[256];
  int t = threadIdx.x;
  int v = (t < nb) ? bsum[t] : 0;
  sd[t] = v;
  __syncthreads();
  for (int off = 1; off < 256; off <<= 1) {
    int add = (t >= off) ? sd[t - off] : 0;
    __syncthreads();
    sd[t] += add;
    __syncthreads();
  }
  bsum[t] = sd[t] - v;  // exclusive block offsets
  if (t == 0) rp[NN] = NE;
}

__global__ __launch_bounds__(256) void scan_add(int* __restrict__ rp,
                                                const int* __restrict__ bsum,
                                                int* __restrict__ nxt) {
  int t = threadIdx.x;
  int base = blockIdx.x * 1024 + t * 4;
  int off = bsum[blockIdx.x];
#pragma unroll
  for (int j = 0; j < 4; ++j) {
    int i = base + j;
    if (i < NN) {
      int val = rp[i] + off;
      rp[i] = val;
      nxt[i] = val;
    }
  }
}

__global__ __launch_bounds__(256) void scatter_kernel(
    const int* __restrict__ esrc, const int* __restrict__ edst,
    int* __restrict__ nxt, int* __restrict__ slotArr, int* __restrict__ psrc) {
  int e = blockIdx.x * 256 + threadIdx.x;
  if (e < NE) {
    int d = edst[e];
    int pos = atomAddI(&nxt[d], 1);
    slotArr[e] = pos;
    psrc[pos] = esrc[e];
  }
}

// ---------------- edge kernel: fc[slot] = sigmoid(h[src]@Ufw^T+b)*c[src] ------
#define F_AS 72
#define F_BS 72

__global__ __launch_bounds__(256) void edge_fc_kernel(
    const float* __restrict__ h, const float* __restrict__ c,
    const unsigned short* __restrict__ Wfb, const float* __restrict__ Ufb,
    const int* __restrict__ esrc, const int* __restrict__ slotArr,
    unsigned short* __restrict__ fcb) {
  __shared__ __align__(16) unsigned short Als[64 * F_AS];
  __shared__ __align__(16) unsigned short Bls[256 * F_BS];
  __shared__ int srcl[64], slotl[64];

  const int tid = threadIdx.x;
  const int e0 = blockIdx.x * 64;
  if (tid < 64) { srcl[tid] = esrc[e0 + tid]; slotl[tid] = slotArr[e0 + tid]; }
  __syncthreads();

  const int lane = tid & 63;
  const int wv = tid >> 6;
  const int wm = wv >> 1, wn = wv & 1;
  const int cbase = lane & 15;
  const int kg = lane >> 4;

  f32x4 acc[2][8];
#pragma unroll
  for (int i = 0; i < 2; ++i)
#pragma unroll
    for (int j = 0; j < 8; ++j) acc[i][j] = {0.f, 0.f, 0.f, 0.f};

  const int arow = tid >> 2;
  const int acg = tid & 3;
  const float* hrow = h + (size_t)srcl[arow] * HD;

  for (int kc = 0; kc < 4; ++kc) {
    const int k0 = kc * 64;
    const float4* s4 = (const float4*)(hrow + k0 + acg * 16);
    float4 q0 = s4[0], q1 = s4[1], q2 = s4[2], q3 = s4[3];
    short8 p0, p1;
    p0[0] = f2bf(q0.x); p0[1] = f2bf(q0.y); p0[2] = f2bf(q0.z); p0[3] = f2bf(q0.w);
    p0[4] = f2bf(q1.x); p0[5] = f2bf(q1.y); p0[6] = f2bf(q1.z); p0[7] = f2bf(q1.w);
    p1[0] = f2bf(q2.x); p1[1] = f2bf(q2.y); p1[2] = f2bf(q2.z); p1[3] = f2bf(q2.w);
    p1[4] = f2bf(q3.x); p1[5] = f2bf(q3.y); p1[6] = f2bf(q3.z); p1[7] = f2bf(q3.w);
    short8* ap = (short8*)&Als[arow * F_AS + acg * 16];
    ap[0] = p0; ap[1] = p1;
#pragma unroll
    for (int i = 0; i < 8; ++i) {
      int f = tid + 256 * i;
      int row = f >> 3, ch = f & 7;
      short8 vb = *(const short8*)(Wfb + row * 256 + k0 + ch * 8);
      *(short8*)&Bls[row * F_BS + ch * 8] = vb;
    }
    __syncthreads();
#pragma unroll
    for (int ks = 0; ks < 2; ++ks) {
      short8 a0 = *(const short8*)&Als[(wm * 32 + cbase) * F_AS + ks * 32 + kg * 8];
      short8 a1 = *(const short8*)&Als[(wm * 32 + 16 + cbase) * F_AS + ks * 32 + kg * 8];
#pragma unroll
      for (int nt = 0; nt < 8; ++nt) {
        short8 b = *(const short8*)&Bls[(wn * 128 + nt * 16 + cbase) * F_BS + ks * 32 + kg * 8];
        acc[0][nt] = __builtin_amdgcn_mfma_f32_16x16x32_bf16(a0, b, acc[0][nt], 0, 0, 0);
        acc[1][nt] = __builtin_amdgcn_mfma_f32_16x16x32_bf16(a1, b, acc[1][nt], 0, 0, 0);
      }
    }
    __syncthreads();
  }
  const int rsub = kg * 4;
#pragma unroll
  for (int nt = 0; nt < 8; ++nt) {
    const int coln = wn * 128 + nt * 16 + cbase;
    const float bias = Ufb[coln];
#pragma unroll
    for (int mt = 0; mt < 2; ++mt) {
#pragma unroll
      for (int j = 0; j < 4; ++j) {
        const int el = wm * 32 + mt * 16 + rsub + j;
        const float fg = sigmoidf_(acc[mt][nt][j] + bias);
        const float cv = c[(size_t)srcl[el] * HD + coln];
        fcb[(size_t)slotl[el] * HD + coln] = f2bf(fg * cv);
      }
    }
  }
}

// ---------------- fused gather + iou (R2 structure, fixed): -------------------
// 64 nodes/block, 512 threads (8 waves 2M x 4N). LDS = Hls 32KB + Cls 33KB
// (no B-LDS: B frags read per-wave from packed Bp in L2 — R6 showed this is
// free). Exactly ONE barrier (after gather); GEMM phase is barrier-free so
// waves drift apart and cover each other's load latency. (512,2) gives the
// compiler a 256-reg budget for real double-buffering (R6's 60-reg allocation
// serialized the pipeline).
#define HLS_SWZ(row, byteoff) (((row) * 512 + (byteoff)) ^ (((row) & 7) << 4))

__global__ __launch_bounds__(512, 2) void iou_fused_kernel(
    const float* __restrict__ x, const float* __restrict__ h,
    const unsigned short* __restrict__ Bp, const float* __restrict__ bperm,
    const int* __restrict__ rp, const int* __restrict__ psrc,
    const unsigned short* __restrict__ fcb, float* __restrict__ out) {
  __shared__ __align__(16) unsigned char HlsB[64 * 512];  // bf16 h_tild, swizzled
  __shared__ __align__(4) unsigned short Cls[64 * 258];   // bf16 c_agg

  const int tid = threadIdx.x;
  const int r0 = blockIdx.x * 64;

  // ---- phase 1: gather children; h_tild -> Hls, c_agg -> Cls ----
  {
    const int node = tid >> 3;  // 0..63
    const int cg = tid & 7;     // 32 cols each
    const int n = r0 + node;
    const int s0 = rp[n], s1 = rp[n + 1];
    float4 hs[8], cs[8];
#pragma unroll
    for (int q = 0; q < 8; ++q) { hs[q] = {0.f, 0.f, 0.f, 0.f}; cs[q] = {0.f, 0.f, 0.f, 0.f}; }
    for (int s = s0; s < s1; ++s) {
      const int src = psrc[s];
      const float4* hp = (const float4*)(h + (size_t)src * HD + cg * 32);
#pragma unroll
      for (int q = 0; q < 8; ++q) {
        float4 v = hp[q];
        hs[q].x += v.x; hs[q].y += v.y; hs[q].z += v.z; hs[q].w += v.w;
      }
      const short8* fp = (const short8*)(fcb + (size_t)s * HD + cg * 32);
#pragma unroll
      for (int q = 0; q < 4; ++q) {
        short8 w = fp[q];
        cs[2 * q].x     += bf2f((unsigned short)w[0]);
        cs[2 * q].y     += bf2f((unsigned short)w[1]);
        cs[2 * q].z     += bf2f((unsigned short)w[2]);
        cs[2 * q].w     += bf2f((unsigned short)w[3]);
        cs[2 * q + 1].x += bf2f((unsigned short)w[4]);
        cs[2 * q + 1].y += bf2f((unsigned short)w[5]);
        cs[2 * q + 1].z += bf2f((unsigned short)w[6]);
        cs[2 * q + 1].w += bf2f((unsigned short)w[7]);
      }
    }
#pragma unroll
    for (int q = 0; q < 4; ++q) {
      short8 hp8;
      hp8[0] = f2bf(hs[2 * q].x);     hp8[1] = f2bf(hs[2 * q].y);
      hp8[2] = f2bf(hs[2 * q].z);     hp8[3] = f2bf(hs[2 * q].w);
      hp8[4] = f2bf(hs[2 * q + 1].x); hp8[5] = f2bf(hs[2 * q + 1].y);
      hp8[6] = f2bf(hs[2 * q + 1].z); hp8[7] = f2bf(hs[2 * q + 1].w);
      *(short8*)&HlsB[HLS_SWZ(node, cg * 64 + q * 16)] = hp8;
      unsigned short* cd = &Cls[node * 258 + cg * 32 + q * 8];
      cd[0] = f2bf(cs[2 * q].x);     cd[1] = f2bf(cs[2 * q].y);
      cd[2] = f2bf(cs[2 * q].z);     cd[3] = f2bf(cs[2 * q].w);
      cd[4] = f2bf(cs[2 * q + 1].x); cd[5] = f2bf(cs[2 * q + 1].y);
      cd[6] = f2bf(cs[2 * q + 1].z); cd[7] = f2bf(cs[2 * q + 1].w);
    }
  }
  __syncthreads();  // the ONLY barrier

  // ---- phase 2: GEMM, barrier-free ----
  const int lane = tid & 63;
  const int wv = tid >> 6;
  const int wm = wv >> 2, wn = wv & 3;  // 2M x 4N
  const int cbase = lane & 15;
  const int kg = lane >> 4;
  const int row0l = wm * 32 + cbase;    // local row
  const float* pX0 = x + (size_t)(r0 + row0l) * HD;
  const float* pX1 = x + (size_t)(r0 + row0l + 16) * HD;
  const char* pB = (const char*)Bp + ((size_t)(wn * 12) * 64 + lane) * 16;

  f32x4 acc[2][12];
#pragma unroll
  for (int m = 0; m < 2; ++m)
#pragma unroll
    for (int t = 0; t < 12; ++t) acc[m][t] = {0.f, 0.f, 0.f, 0.f};

  short8 Bf[2][12];
  float4 Xr[2][4];

#pragma unroll
  for (int t = 0; t < 12; ++t) Bf[0][t] = *(const short8*)(pB + t * 1024);
  Xr[0][0] = *(const float4*)(pX0 + kg * 8);
  Xr[0][1] = *(const float4*)(pX0 + kg * 8 + 4);
  Xr[0][2] = *(const float4*)(pX1 + kg * 8);
  Xr[0][3] = *(const float4*)(pX1 + kg * 8 + 4);

#pragma unroll
  for (int kc = 0; kc < 16; ++kc) {
    const int cur = kc & 1, nxt = cur ^ 1;
    if (kc < 15) {
      const char* pBn = pB + (kc + 1) * 49152;
#pragma unroll
      for (int t = 0; t < 12; ++t) Bf[nxt][t] = *(const short8*)(pBn + t * 1024);
      if (kc + 1 < 8) {
        const int k0n = (kc + 1) * 32;
        Xr[nxt][0] = *(const float4*)(pX0 + k0n + kg * 8);
        Xr[nxt][1] = *(const float4*)(pX0 + k0n + kg * 8 + 4);
        Xr[nxt][2] = *(const float4*)(pX1 + k0n + kg * 8);
        Xr[nxt][3] = *(const float4*)(pX1 + k0n + kg * 8 + 4);
      }
    }
    short8 a0, a1;
    if (kc < 8) {
      float4 u0 = Xr[cur][0], u1 = Xr[cur][1], u2 = Xr[cur][2], u3 = Xr[cur][3];
      a0[0] = f2bf(u0.x); a0[1] = f2bf(u0.y); a0[2] = f2bf(u0.z); a0[3] = f2bf(u0.w);
      a0[4] = f2bf(u1.x); a0[5] = f2bf(u1.y); a0[6] = f2bf(u1.z); a0[7] = f2bf(u1.w);
      a1[0] = f2bf(u2.x); a1[1] = f2bf(u2.y); a1[2] = f2bf(u2.z); a1[3] = f2bf(u2.w);
      a1[4] = f2bf(u3.x); a1[5] = f2bf(u3.y); a1[6] = f2bf(u3.z); a1[7] = f2bf(u3.w);
    } else {
      const int bo = (kc - 8) * 64 + kg * 16;
      a0 = *(const short8*)&HlsB[HLS_SWZ(row0l, bo)];
      a1 = *(const short8*)&HlsB[HLS_SWZ(row0l + 16, bo)];
    }
#pragma unroll
    for (int tt = 0; tt < 12; ++tt) {
      acc[0][tt] = __builtin_amdgcn_mfma_f32_16x16x32_bf16(a0, Bf[cur][tt], acc[0][tt], 0, 0, 0);
      acc[1][tt] = __builtin_amdgcn_mfma_f32_16x16x32_bf16(a1, Bf[cur][tt], acc[1][tt], 0, 0, 0);
    }
  }

  // ---- epilogue: gates + outputs (gate triples in consecutive tiles) ----
  float* outc = out + (size_t)NN * HD;
  const int rsub = kg * 4;
#pragma unroll
  for (int t3 = 0; t3 < 4; ++t3) {
    const int T = wn * 12 + 3 * t3;
    const float bi = bperm[(T + 0) * 16 + cbase];
    const float bo = bperm[(T + 1) * 16 + cbase];
    const float bu = bperm[(T + 2) * 16 + cbase];
    const int j = (wn * 4 + t3) * 16 + cbase;
#pragma unroll
    for (int mf = 0; mf < 2; ++mf) {
#pragma unroll
      for (int jr = 0; jr < 4; ++jr) {
        const int rl = wm * 32 + mf * 16 + rsub + jr;
        const size_t idx = (size_t)(r0 + rl) * HD + j;
        const float iv = sigmoidf_(acc[mf][3 * t3 + 0][jr] + bi);
        const float ov = sigmoidf_(acc[mf][3 * t3 + 1][jr] + bo);
        const float uv = tanhf_(acc[mf][3 * t3 + 2][jr] + bu);
        const float cagg = bf2f(Cls[rl * 258 + j]);
        const float cn = iv * uv + cagg;
        out[idx] = ov * tanhf_(cn);
        outc[idx] = cn;
      }
    }
  }
}

// ================= fallback path (R1 kernels, used when ws is too small) ======
__global__ __launch_bounds__(256) void edge_kernel(
    const float* __restrict__ h, const float* __restrict__ c,
    const unsigned short* __restrict__ Wfb, const float* __restrict__ Ufb,
    const int* __restrict__ esrc, const int* __restrict__ edst,
    float* h_tild, float* c_agg) {
  __shared__ __align__(16) unsigned short Als[64 * F_AS];
  __shared__ __align__(16) unsigned short Bls[256 * F_BS];
  __shared__ int srcl[64], dstl[64];

  const int tid = threadIdx.x;
  const int e0 = blockIdx.x * 64;
  if (tid < 64) { srcl[tid] = esrc[e0 + tid]; dstl[tid] = edst[e0 + tid]; }
  __syncthreads();

  const int lane = tid & 63;
  const int wv = tid >> 6;
  const int wm = wv >> 1, wn = wv & 1;
  const int cbase = lane & 15;
  const int kg = lane >> 4;

  f32x4 acc[2][8];
#pragma unroll
  for (int i = 0; i < 2; ++i)
#pragma unroll
    for (int j = 0; j < 8; ++j) acc[i][j] = {0.f, 0.f, 0.f, 0.f};

  const int arow = tid >> 2;
  const int acg = tid & 3;
  const float* hrow = h + (size_t)srcl[arow] * HD;
  float* htrow = h_tild + (size_t)dstl[arow] * HD;

  for (int kc = 0; kc < 4; ++kc) {
    const int k0 = kc * 64;
    const float4* s4 = (const float4*)(hrow + k0 + acg * 16);
    float4 q0 = s4[0], q1 = s4[1], q2 = s4[2], q3 = s4[3];
    short8 p0, p1;
    p0[0] = f2bf(q0.x); p0[1] = f2bf(q0.y); p0[2] = f2bf(q0.z); p0[3] = f2bf(q0.w);
    p0[4] = f2bf(q1.x); p0[5] = f2bf(q1.y); p0[6] = f2bf(q1.z); p0[7] = f2bf(q1.w);
    p1[0] = f2bf(q2.x); p1[1] = f2bf(q2.y); p1[2] = f2bf(q2.z); p1[3] = f2bf(q2.w);
    p1[4] = f2bf(q3.x); p1[5] = f2bf(q3.y); p1[6] = f2bf(q3.z); p1[7] = f2bf(q3.w);
    short8* ap = (short8*)&Als[arow * F_AS + acg * 16];
    ap[0] = p0; ap[1] = p1;
    {
      float* hp = htrow + k0 + acg * 16;
      atomAddF(hp + 0, q0.x);  atomAddF(hp + 1, q0.y);
      atomAddF(hp + 2, q0.z);  atomAddF(hp + 3, q0.w);
      atomAddF(hp + 4, q1.x);  atomAddF(hp + 5, q1.y);
      atomAddF(hp + 6, q1.z);  atomAddF(hp + 7, q1.w);
      atomAddF(hp + 8, q2.x);  atomAddF(hp + 9, q2.y);
      atomAddF(hp + 10, q2.z); atomAddF(hp + 11, q2.w);
      atomAddF(hp + 12, q3.x); atomAddF(hp + 13, q3.y);
      atomAddF(hp + 14, q3.z); atomAddF(hp + 15, q3.w);
    }
#pragma unroll
    for (int i = 0; i < 8; ++i) {
      int f = tid + 256 * i;
      int row = f >> 3, ch = f & 7;
      short8 vb = *(const short8*)(Wfb + row * 256 + k0 + ch * 8);
      *(short8*)&Bls[row * F_BS + ch * 8] = vb;
    }
    __syncthreads();
#pragma unroll
    for (int ks = 0; ks < 2; ++ks) {
      short8 a0 = *(const short8*)&Als[(wm * 32 + cbase) * F_AS + ks * 32 + kg * 8];
      short8 a1 = *(const short8*)&Als[(wm * 32 + 16 + cbase) * F_AS + ks * 32 + kg * 8];
#pragma unroll
      for (int nt = 0; nt < 8; ++nt) {
        short8 b = *(const short8*)&Bls[(wn * 128 + nt * 16 + cbase) * F_BS + ks * 32 + kg * 8];
        acc[0][nt] = __builtin_amdgcn_mfma_f32_16x16x32_bf16(a0, b, acc[0][nt], 0, 0, 0);
        acc[1][nt] = __builtin_amdgcn_mfma_f32_16x16x32_bf16(a1, b, acc[1][nt], 0, 0, 0);
      }
    }
    __syncthreads();
  }
  const int rsub = kg * 4;
#pragma unroll
  for (int nt = 0; nt < 8; ++nt) {
    const int coln = wn * 128 + nt * 16 + cbase;
    const float bias = Ufb[coln];
#pragma unroll
    for (int mt = 0; mt < 2; ++mt) {
#pragma unroll
      for (int j = 0; j < 4; ++j) {
        const int el = wm * 32 + mt * 16 + rsub + j;
        const float fg = sigmoidf_(acc[mt][nt][j] + bias);
        const float cv = c[(size_t)srcl[el] * HD + coln];
        atomAddF(c_agg + (size_t)dstl[el] * HD + coln, fg * cv);
      }
    }
  }
}

#define I_AS 40
#define I_BS 40

__global__ __launch_bounds__(256) void iou_kernel(
    const float* __restrict__ x, const unsigned short* __restrict__ Wioub,
    const unsigned short* __restrict__ Uioub, const float* __restrict__ bperm,
    float* out) {
  __shared__ __align__(16) unsigned short Als[32 * I_AS];
  __shared__ __align__(16) unsigned short Bls[768 * I_BS];

  const int tid = threadIdx.x;
  const int lane = tid & 63;
  const int wv = tid >> 6;
  const int wm = wv >> 1, wn = wv & 1;
  const int cbase = lane & 15;
  const int kg = lane >> 4;
  const int r0 = blockIdx.x * 32;

  float* h_tild = out;
  float* c_agg = out + (size_t)NN * HD;

  f32x4 acc[24];
#pragma unroll
  for (int t = 0; t < 24; ++t) acc[t] = {0.f, 0.f, 0.f, 0.f};

  const int arow = tid >> 3;
  const int acg = tid & 7;

  for (int pass = 0; pass < 2; ++pass) {
    const float* As = pass ? h_tild : x;
    const unsigned short* Bs = pass ? Uioub : Wioub;
    for (int kc = 0; kc < 8; ++kc) {
      const int k0 = kc * 32;
      float4 q = *(const float4*)(As + (size_t)(r0 + arow) * HD + k0 + acg * 4);
      short4v p;
      p[0] = f2bf(q.x); p[1] = f2bf(q.y); p[2] = f2bf(q.z); p[3] = f2bf(q.w);
      *(short4v*)&Als[arow * I_AS + acg * 4] = p;
#pragma unroll
      for (int i = 0; i < 12; ++i) {
        int f = tid + 256 * i;
        int row = f >> 2, ch = f & 3;
        short8 vb = *(const short8*)(Bs + row * 256 + k0 + ch * 8);
        *(short8*)&Bls[row * I_BS + ch * 8] = vb;
      }
      __syncthreads();
      short8 a = *(const short8*)&Als[(wm * 16 + cbase) * I_AS + kg * 8];
#pragma unroll
      for (int tt = 0; tt < 24; ++tt) {
        short8 b = *(const short8*)&Bls[((wn * 24 + tt) * 16 + cbase) * I_BS + kg * 8];
        acc[tt] = __builtin_amdgcn_mfma_f32_16x16x32_bf16(a, b, acc[tt], 0, 0, 0);
      }
      __syncthreads();
    }
  }
  const int rsub = kg * 4;
#pragma unroll
  for (int t3 = 0; t3 < 8; ++t3) {
    const int T = wn * 24 + 3 * t3;
    const float bi = bperm[(T + 0) * 16 + cbase];
    const float bo = bperm[(T + 1) * 16 + cbase];
    const float bu = bperm[(T + 2) * 16 + cbase];
    const int j = (wn * 8 + t3) * 16 + cbase;
#pragma unroll
    for (int jr = 0; jr < 4; ++jr) {
      const int r = r0 + wm * 16 + rsub + jr;
      const size_t idx = (size_t)r * HD + j;
      const float iv = sigmoidf_(acc[3 * t3 + 0][jr] + bi);
      const float ov = sigmoidf_(acc[3 * t3 + 1][jr] + bo);
      const float uv = tanhf_(acc[3 * t3 + 2][jr] + bu);
      const float cn = iv * uv + c_agg[idx];
      out[idx] = ov * tanhf_(cn);
      c_agg[idx] = cn;
    }
  }
}

extern "C" void kernel_launch(void* const* d_in, const int* in_sizes, int n_in,
                              void* d_out, int out_size, void* d_ws, size_t ws_size,
                              hipStream_t stream) {
  const float* x    = (const float*)d_in[0];
  const float* h    = (const float*)d_in[1];
  const float* c    = (const float*)d_in[2];
  const float* Wiou = (const float*)d_in[3];
  const float* Uiou = (const float*)d_in[4];
  const float* biou = (const float*)d_in[5];
  const float* Ufw  = (const float*)d_in[6];
  const float* Ufb  = (const float*)d_in[7];
  const int* esrc   = (const int*)d_in[8];
  const int* edst   = (const int*)d_in[9];
  float* out = (float*)d_out;

  char* ws = (char*)d_ws;
  unsigned short* Wfb   = (unsigned short*)(ws + OFF_WFB);
  unsigned short* Bp    = (unsigned short*)(ws + OFF_BP);
  float* bperm          = (float*)(ws + OFF_BPERM);

  if (ws_size >= WS_NEED) {
    int* rpp  = (int*)(ws + OFF_ROWPTR);
    int* nxt  = (int*)(ws + OFF_NEXT);
    int* slot = (int*)(ws + OFF_SLOT);
    int* psrc = (int*)(ws + OFF_PSRC);
    int* bsum = (int*)(ws + OFF_BSUM);
    unsigned short* fcb = (unsigned short*)(ws + OFF_FC);

    (void)hipMemsetAsync(nxt, 0, (size_t)NN * sizeof(int), stream);
    prep_kernel<<<1795, 256, 0, stream>>>(Ufw, Wiou, Uiou, biou, Wfb, Bp, bperm);
    hist_kernel<<<(NE + 255) / 256, 256, 0, stream>>>(edst, nxt);
    scan_part<<<(NN + 1023) / 1024, 256, 0, stream>>>(nxt, rpp, bsum);
    scan_top<<<1, 256, 0, stream>>>(bsum, rpp, (NN + 1023) / 1024);
    scan_add<<<(NN + 1023) / 1024, 256, 0, stream>>>(rpp, bsum, nxt);
    scatter_kernel<<<(NE + 255) / 256, 256, 0, stream>>>(esrc, edst, nxt, slot, psrc);
    edge_fc_kernel<<<NE / 64, 256, 0, stream>>>(h, c, Wfb, Ufb, esrc, slot, fcb);
    iou_fused_kernel<<<NN / 64, 512, 0, stream>>>(x, h, Bp, bperm, rpp, psrc, fcb, out);
  } else {
    // fallback: R1 scatter-atomic path (row-major permuted weights in BP region)
    unsigned short* Wioub = (unsigned short*)(ws + OFF_BP);
    unsigned short* Uioub = (unsigned short*)(ws + OFF_BP + 393216);
    (void)hipMemsetAsync(d_out, 0, (size_t)out_size * sizeof(float), stream);
    prep_fb_kernel<<<1795, 256, 0, stream>>>(Ufw, Wiou, Uiou, biou, Wfb, Wioub, Uioub, bperm);
    edge_kernel<<<NE / 64, 256, 0, stream>>>(h, c, Wfb, Ufb, esrc, edst,
                                             out, out + (size_t)NN * HD);
    iou_kernel<<<NN / 32, 256, 0, stream>>>(x, Wioub, Uioub, bperm, out);
  }
}

// Round 8
// 870.487 us; speedup vs baseline: 1.2901x; 1.2901x over previous
//
#include <hip/hip_runtime.h>

#define NN 200000
#define NE 200000
#define HD 256

typedef __attribute__((ext_vector_type(8))) short short8;
typedef __attribute__((ext_vector_type(4))) short short4v;
typedef __attribute__((ext_vector_type(4))) float f32x4;

static __device__ __forceinline__ unsigned short f2bf(float f) {
  unsigned u = __float_as_uint(f);
  u = (u + 0x7FFFu + ((u >> 16) & 1u)) >> 16;
  return (unsigned short)u;
}
static __device__ __forceinline__ float bf2f(unsigned short u) {
  return __uint_as_float(((unsigned)u) << 16);
}
static __device__ __forceinline__ float sigmoidf_(float x) {
  return 1.0f / (1.0f + __expf(-x));
}
static __device__ __forceinline__ float tanhf_(float x) {
  return 2.0f / (1.0f + __expf(-2.0f * x)) - 1.0f;
}
static __device__ __forceinline__ void atomAddF(float* p, float v) {
  __hip_atomic_fetch_add(p, v, __ATOMIC_RELAXED, __HIP_MEMORY_SCOPE_AGENT);
}
static __device__ __forceinline__ int atomAddI(int* p, int v) {
  return __hip_atomic_fetch_add(p, v, __ATOMIC_RELAXED, __HIP_MEMORY_SCOPE_AGENT);
}

#if defined(__HIP_DEVICE_COMPILE__)
static __device__ __forceinline__ void gload_lds16(const void* g, void* l) {
  __builtin_amdgcn_global_load_lds(
      (const __attribute__((address_space(1))) void*)g,
      (__attribute__((address_space(3))) void*)l, 16, 0, 0);
}
#else
static __device__ __forceinline__ void gload_lds16(const void*, void*) {}
#endif

// ws layout (bytes)
#define OFF_WFB    0u           // bf16[256*256]
#define OFF_BP     131072u      // packed B fragments: bf16[16*48*64*8] = 786432 B
#define OFF_BPERM  917504u      // f32[768]
#define OFF_ROWPTR 920576u      // int[NN+1]
#define OFF_NEXT   1720832u     // int[NN]
#define OFF_SLOT   2520832u     // int[NE]
#define OFF_PSRC   3320832u     // int[NE]
#define OFF_BSUM   4120832u     // int[256]
#define OFF_ZERO   4121856u     // 1024 B of zeros
#define OFF_FC     4122880u     // bf16[NE*HD]
#define WS_NEED    106522880ull

// --------- prep (fast path): Wfb bf16; B fragment-packed; bias gate-permuted --
__global__ __launch_bounds__(256) void prep_kernel(
    const float* __restrict__ Ufw, const float* __restrict__ Wiou,
    const float* __restrict__ Uiou, const float* __restrict__ biou,
    unsigned short* __restrict__ Wfb, unsigned short* __restrict__ Bp,
    float* __restrict__ bperm) {
  int idx = blockIdx.x * 256 + threadIdx.x;
  if (idx < 65536) {
    Wfb[idx] = f2bf(Ufw[idx]);
  } else if (idx < 458752) {
    int o = idx - 65536;
    int kc = o / 24576;
    int rem = o - kc * 24576;
    int tt = rem / 512;
    int rem2 = rem - tt * 512;
    int ln = rem2 >> 3, e = rem2 & 7;
    int cc = ln & 15, kgp = ln >> 4;
    int kk = kc * 32 + kgp * 8 + e;
    int g = tt % 3, tj = tt / 3;
    int orow = g * 256 + tj * 16 + cc;
    float v = (kk < 256) ? Wiou[orow * 256 + kk] : Uiou[orow * 256 + (kk - 256)];
    Bp[o] = f2bf(v);
  } else if (idx < 459520) {
    int j2 = idx - 458752;
    int T = j2 >> 4, cc = j2 & 15;
    int g = T % 3, tj = T / 3;
    bperm[j2] = biou[g * 256 + tj * 16 + cc];
  }
}

// --------- prep (fallback): plain gate-permuted row-major W/U ---------------
__global__ __launch_bounds__(256) void prep_fb_kernel(
    const float* __restrict__ Ufw, const float* __restrict__ Wiou,
    const float* __restrict__ Uiou, const float* __restrict__ biou,
    unsigned short* __restrict__ Wfb, unsigned short* __restrict__ Wioub,
    unsigned short* __restrict__ Uioub, float* __restrict__ bperm) {
  int idx = blockIdx.x * 256 + threadIdx.x;
  if (idx < 65536) {
    Wfb[idx] = f2bf(Ufw[idx]);
  } else if (idx < 262144) {
    int i2 = idx - 65536;
    int rp = i2 >> 8, k = i2 & 255;
    int T = rp >> 4, cc = rp & 15;
    int g = T % 3, tj = T / 3;
    Wioub[i2] = f2bf(Wiou[(g * 256 + tj * 16 + cc) * 256 + k]);
  } else if (idx < 458752) {
    int i2 = idx - 262144;
    int rp = i2 >> 8, k = i2 & 255;
    int T = rp >> 4, cc = rp & 15;
    int g = T % 3, tj = T / 3;
    Uioub[i2] = f2bf(Uiou[(g * 256 + tj * 16 + cc) * 256 + k]);
  } else if (idx < 459520) {
    int j2 = idx - 458752;
    int T = j2 >> 4, cc = j2 & 15;
    int g = T % 3, tj = T / 3;
    bperm[j2] = biou[g * 256 + tj * 16 + cc];
  }
}

// ---------------- CSR build ----------------
__global__ __launch_bounds__(256) void hist_kernel(const int* __restrict__ edst,
                                                   int* __restrict__ cnt) {
  int e = blockIdx.x * 256 + threadIdx.x;
  if (e < NE) atomAddI(&cnt[edst[e]], 1);
}

__global__ __launch_bounds__(256) void scan_part(const int* __restrict__ cnt,
                                                 int* __restrict__ rp,
                                                 int* __restrict__ bsum) {
  __shared__ int sd[256];
  int t = threadIdx.x;
  int base = blockIdx.x * 1024 + t * 4;
  int v0 = (base + 0 < NN) ? cnt[base + 0] : 0;
  int v1 = (base + 1 < NN) ? cnt[base + 1] : 0;
  int v2 = (base + 2 < NN) ? cnt[base + 2] : 0;
  int v3 = (base + 3 < NN) ? cnt[base + 3] : 0;
  int s = v0 + v1 + v2 + v3;
  sd[t] = s;
  __syncthreads();
  for (int off = 1; off < 256; off <<= 1) {
    int add = (t >= off) ? sd[t - off] : 0;
    __syncthreads();
    sd[t] += add;
    __syncthreads();
  }
  int run = sd[t] - s;  // exclusive
  if (base + 0 < NN) rp[base + 0] = run; run += v0;
  if (base + 1 < NN) rp[base + 1] = run; run += v1;
  if (base + 2 < NN) rp[base + 2] = run; run += v2;
  if (base + 3 < NN) rp[base + 3] = run;
  if (t == 255) bsum[blockIdx.x] = sd[255];
}

__global__ __launch_bounds__(256) void scan_top(int* __restrict__ bsum,
                                                int* __restrict__ rp, int nb) {
  __shared__ int sd[256];
  int t = threadIdx.x;
  int v = (t < nb) ? bsum[t] : 0;
  sd[t] = v;
  __syncthreads();
  for (int off = 1; off < 256; off <<= 1) {
    int add = (t >= off) ? sd[t - off] : 0;
    __syncthreads();
    sd[t] += add;
    __syncthreads();
  }
  bsum[t] = sd[t] - v;  // exclusive block offsets
  if (t == 0) rp[NN] = NE;
}

__global__ __launch_bounds__(256) void scan_add(int* __restrict__ rp,
                                                const int* __restrict__ bsum,
                                                int* __restrict__ nxt) {
  int t = threadIdx.x;
  int base = blockIdx.x * 1024 + t * 4;
  int off = bsum[blockIdx.x];
#pragma unroll
  for (int j = 0; j < 4; ++j) {
    int i = base + j;
    if (i < NN) {
      int val = rp[i] + off;
      rp[i] = val;
      nxt[i] = val;
    }
  }
}

__global__ __launch_bounds__(256) void scatter_kernel(
    const int* __restrict__ esrc, const int* __restrict__ edst,
    int* __restrict__ nxt, int* __restrict__ slotArr, int* __restrict__ psrc) {
  int e = blockIdx.x * 256 + threadIdx.x;
  if (e < NE) {
    int d = edst[e];
    int pos = atomAddI(&nxt[d], 1);
    slotArr[e] = pos;
    psrc[pos] = esrc[e];
  }
}

// ---------------- edge kernel: fc[slot] = sigmoid(h[src]@Ufw^T+b)*c[src] ------
#define F_AS 72
#define F_BS 72

__global__ __launch_bounds__(256) void edge_fc_kernel(
    const float* __restrict__ h, const float* __restrict__ c,
    const unsigned short* __restrict__ Wfb, const float* __restrict__ Ufb,
    const int* __restrict__ esrc, const int* __restrict__ slotArr,
    unsigned short* __restrict__ fcb) {
  __shared__ __align__(16) unsigned short Als[64 * F_AS];
  __shared__ __align__(16) unsigned short Bls[256 * F_BS];
  __shared__ int srcl[64], slotl[64];

  const int tid = threadIdx.x;
  const int e0 = blockIdx.x * 64;
  if (tid < 64) { srcl[tid] = esrc[e0 + tid]; slotl[tid] = slotArr[e0 + tid]; }
  __syncthreads();

  const int lane = tid & 63;
  const int wv = tid >> 6;
  const int wm = wv >> 1, wn = wv & 1;
  const int cbase = lane & 15;
  const int kg = lane >> 4;

  f32x4 acc[2][8];
#pragma unroll
  for (int i = 0; i < 2; ++i)
#pragma unroll
    for (int j = 0; j < 8; ++j) acc[i][j] = {0.f, 0.f, 0.f, 0.f};

  const int arow = tid >> 2;
  const int acg = tid & 3;
  const float* hrow = h + (size_t)srcl[arow] * HD;

  for (int kc = 0; kc < 4; ++kc) {
    const int k0 = kc * 64;
    const float4* s4 = (const float4*)(hrow + k0 + acg * 16);
    float4 q0 = s4[0], q1 = s4[1], q2 = s4[2], q3 = s4[3];
    short8 p0, p1;
    p0[0] = f2bf(q0.x); p0[1] = f2bf(q0.y); p0[2] = f2bf(q0.z); p0[3] = f2bf(q0.w);
    p0[4] = f2bf(q1.x); p0[5] = f2bf(q1.y); p0[6] = f2bf(q1.z); p0[7] = f2bf(q1.w);
    p1[0] = f2bf(q2.x); p1[1] = f2bf(q2.y); p1[2] = f2bf(q2.z); p1[3] = f2bf(q2.w);
    p1[4] = f2bf(q3.x); p1[5] = f2bf(q3.y); p1[6] = f2bf(q3.z); p1[7] = f2bf(q3.w);
    short8* ap = (short8*)&Als[arow * F_AS + acg * 16];
    ap[0] = p0; ap[1] = p1;
#pragma unroll
    for (int i = 0; i < 8; ++i) {
      int f = tid + 256 * i;
      int row = f >> 3, ch = f & 7;
      short8 vb = *(const short8*)(Wfb + row * 256 + k0 + ch * 8);
      *(short8*)&Bls[row * F_BS + ch * 8] = vb;
    }
    __syncthreads();
#pragma unroll
    for (int ks = 0; ks < 2; ++ks) {
      short8 a0 = *(const short8*)&Als[(wm * 32 + cbase) * F_AS + ks * 32 + kg * 8];
      short8 a1 = *(const short8*)&Als[(wm * 32 + 16 + cbase) * F_AS + ks * 32 + kg * 8];
#pragma unroll
      for (int nt = 0; nt < 8; ++nt) {
        short8 b = *(const short8*)&Bls[(wn * 128 + nt * 16 + cbase) * F_BS + ks * 32 + kg * 8];
        acc[0][nt] = __builtin_amdgcn_mfma_f32_16x16x32_bf16(a0, b, acc[0][nt], 0, 0, 0);
        acc[1][nt] = __builtin_amdgcn_mfma_f32_16x16x32_bf16(a1, b, acc[1][nt], 0, 0, 0);
      }
    }
    __syncthreads();
  }
  const int rsub = kg * 4;
#pragma unroll
  for (int nt = 0; nt < 8; ++nt) {
    const int coln = wn * 128 + nt * 16 + cbase;
    const float bias = Ufb[coln];
#pragma unroll
    for (int mt = 0; mt < 2; ++mt) {
#pragma unroll
      for (int j = 0; j < 4; ++j) {
        const int el = wm * 32 + mt * 16 + rsub + j;
        const float fg = sigmoidf_(acc[mt][nt][j] + bias);
        const float cv = c[(size_t)srcl[el] * HD + coln];
        fcb[(size_t)slotl[el] * HD + coln] = f2bf(fg * cv);
      }
    }
  }
}

// ---------------- gather kernel: c_agg (f32 -> out c-half), h_tild (bf16 ->
// first-child slot of fcb, which is dead after this thread's reads) ----------
__global__ __launch_bounds__(256) void gather_kernel(
    const float* __restrict__ h, const int* __restrict__ rp,
    const int* __restrict__ psrc, unsigned short* __restrict__ fcb,
    float* __restrict__ cagg) {
  const int tid = threadIdx.x;
  const int node = blockIdx.x * 32 + (tid >> 3);
  const int cg = tid & 7;  // 32 cols per thread
  const int s0 = rp[node], s1 = rp[node + 1];

  float hs[32], cs[32];
#pragma unroll
  for (int q = 0; q < 32; ++q) { hs[q] = 0.f; cs[q] = 0.f; }

  for (int s = s0; s < s1; ++s) {
    const int src = psrc[s];
    const float4* hp = (const float4*)(h + (size_t)src * HD + cg * 32);
    const short8* fp = (const short8*)(fcb + (size_t)s * HD + cg * 32);
#pragma unroll
    for (int q = 0; q < 8; ++q) {
      float4 v = hp[q];
      hs[4 * q + 0] += v.x; hs[4 * q + 1] += v.y;
      hs[4 * q + 2] += v.z; hs[4 * q + 3] += v.w;
    }
#pragma unroll
    for (int q = 0; q < 4; ++q) {
      short8 w = fp[q];
#pragma unroll
      for (int e = 0; e < 8; ++e) cs[8 * q + e] += bf2f((unsigned short)w[e]);
    }
  }
  float4* cp = (float4*)(cagg + (size_t)node * HD + cg * 32);
#pragma unroll
  for (int q = 0; q < 8; ++q) {
    float4 v = {cs[4 * q + 0], cs[4 * q + 1], cs[4 * q + 2], cs[4 * q + 3]};
    cp[q] = v;
  }
  if (s1 > s0) {
    // h_tild bf16 into first-child slot, with the SAME (row&3)-XOR the GEMM's
    // staging expects?  No: staging applies its own source-XOR when reading
    // this row, so store PLAIN layout here.
    short8* hd = (short8*)(fcb + (size_t)s0 * HD + cg * 32);
#pragma unroll
    for (int q = 0; q < 4; ++q) {
      short8 p;
#pragma unroll
      for (int e = 0; e < 8; ++e) p[e] = f2bf(hs[8 * q + e]);
      hd[q] = p;
    }
  }
}

// ---------------- iou GEMM v4 (m97-style): 128 rows x 192 cols, 256 thr ------
// 4 waves, each 32 rows x 192 cols (acc[2][12] = 96 VGPR); BK=32, 16 kc.
// ALL staging via global_load_lds, single-buffered LDS 28.7 KB -> 3 blocks/CU;
// 2 barriers/kc; cross-block TLP is the latency hiding (R3 evidence).
// f32 x-tiles staged with source pre-XOR so LDS frag reads are bank-spread;
// bf16 h_tild rows staged via per-lane source pointers (global src IS per-lane).
__global__ __launch_bounds__(256) void iou_gemm4_kernel(
    const float* __restrict__ x, const unsigned short* __restrict__ Bp,
    const float* __restrict__ bperm, const int* __restrict__ rp,
    const unsigned short* __restrict__ fcb, const char* __restrict__ zpage,
    float* __restrict__ out) {
  __shared__ __align__(16) unsigned char Als[16384];  // f32 x-tile / bf16 ht-tile
  __shared__ __align__(16) unsigned char Bls[12288];  // 12 tiles x 1024 B

  const int tid = threadIdx.x;
  const int lane = tid & 63;
  const int wv = tid >> 6;        // 0..3
  const int cbase = lane & 15;
  const int kg = lane >> 4;

  const int bid = blockIdx.x;
  const int rgrp = bid >> 2;
  const int nq = bid & 3;         // N-quarter: permuted tiles [nq*12, +12)
  const int r0 = rgrp * 128;

  // --- staging source bases (per thread) ---
  // f32 phase: 4 units; unit_i = i*256 + wv*64 + lane; row = rbase + i*32
  const int cI = lane & 7;
  const int rbase = wv * 8 + (lane >> 3);
  const int offX = (cI * 16) ^ ((rbase & 7) << 4);   // source pre-swizzle
  const char* xsrc[4];
#pragma unroll
  for (int i = 0; i < 4; ++i) {
    int rr = r0 + rbase + i * 32; if (rr > NN - 1) rr = NN - 1;
    xsrc[i] = (const char*)x + (size_t)rr * 1024 + offX;
  }
  // bf16 phase: 2 units; row = i*64 + wv*16 + (lane>>2)
  const int cH = lane & 3;
  const char* hsrc[2];
#pragma unroll
  for (int i = 0; i < 2; ++i) {
    const int rl = i * 64 + wv * 16 + (lane >> 2);
    int rr = r0 + rl; if (rr > NN - 1) rr = NN - 1;
    const int s0 = rp[rr], s1 = rp[rr + 1];
    const char* base = (s1 > s0) ? (const char*)(fcb + (size_t)s0 * HD) : zpage;
    hsrc[i] = base + ((cH * 16) ^ ((rl & 3) << 4));
  }
  const char* bsrc = (const char*)Bp + (size_t)nq * 12288 + (wv * 64 + lane) * 16;

  f32x4 acc[2][12];
#pragma unroll
  for (int m = 0; m < 2; ++m)
#pragma unroll
    for (int t = 0; t < 12; ++t) acc[m][t] = {0.f, 0.f, 0.f, 0.f};

  const int frow0 = wv * 32 + cbase;        // A-frag rows (frow1 = +16)
  const int swX = (frow0 & 7) << 4;          // same for frow0/frow0+16
  const int swH = (frow0 & 3) << 4;

  for (int kc = 0; kc < 16; ++kc) {
    // ---- stage (all global_load_lds; LDS dst wave-uniform base) ----
#pragma unroll
    for (int i = 0; i < 3; ++i)
      gload_lds16(bsrc + (size_t)kc * 49152 + i * 4096,
                  Bls + i * 4096 + wv * 1024);
    if (kc < 8) {
#pragma unroll
      for (int i = 0; i < 4; ++i)
        gload_lds16(xsrc[i] + kc * 128, Als + i * 4096 + wv * 1024);
    } else {
#pragma unroll
      for (int i = 0; i < 2; ++i)
        gload_lds16(hsrc[i] + (kc - 8) * 64, Als + i * 4096 + wv * 1024);
    }
    __syncthreads();  // drains vmcnt: tiles ready

    // ---- A fragments ----
    short8 a0, a1;
    if (kc < 8) {
      const unsigned char* ar0 = Als + frow0 * 128;
      const unsigned char* ar1 = Als + (frow0 + 16) * 128;
      float4 q0 = *(const float4*)(ar0 + ((kg * 32) ^ swX));
      float4 q1 = *(const float4*)(ar0 + ((kg * 32 + 16) ^ swX));
      float4 q2 = *(const float4*)(ar1 + ((kg * 32) ^ swX));
      float4 q3 = *(const float4*)(ar1 + ((kg * 32 + 16) ^ swX));
      a0[0] = f2bf(q0.x); a0[1] = f2bf(q0.y); a0[2] = f2bf(q0.z); a0[3] = f2bf(q0.w);
      a0[4] = f2bf(q1.x); a0[5] = f2bf(q1.y); a0[6] = f2bf(q1.z); a0[7] = f2bf(q1.w);
      a1[0] = f2bf(q2.x); a1[1] = f2bf(q2.y); a1[2] = f2bf(q2.z); a1[3] = f2bf(q2.w);
      a1[4] = f2bf(q3.x); a1[5] = f2bf(q3.y); a1[6] = f2bf(q3.z); a1[7] = f2bf(q3.w);
    } else {
      a0 = *(const short8*)(Als + frow0 * 64 + ((kg * 16) ^ swH));
      a1 = *(const short8*)(Als + (frow0 + 16) * 64 + ((kg * 16) ^ swH));
    }
    // ---- 24 MFMA ----
#pragma unroll
    for (int tt = 0; tt < 12; ++tt) {
      short8 b = *(const short8*)(Bls + tt * 1024 + lane * 16);
      acc[0][tt] = __builtin_amdgcn_mfma_f32_16x16x32_bf16(a0, b, acc[0][tt], 0, 0, 0);
      acc[1][tt] = __builtin_amdgcn_mfma_f32_16x16x32_bf16(a1, b, acc[1][tt], 0, 0, 0);
    }
    __syncthreads();  // all waves done reading before next kc overwrites
  }

  // ---- epilogue: gate triples (i,o,u) = tiles 3t3, 3t3+1, 3t3+2 ----
  float* outc = out + (size_t)NN * HD;
#pragma unroll
  for (int t3 = 0; t3 < 4; ++t3) {
    const int TT = nq * 12 + 3 * t3;
    const float bi = bperm[(TT + 0) * 16 + cbase];
    const float bo = bperm[(TT + 1) * 16 + cbase];
    const float bu = bperm[(TT + 2) * 16 + cbase];
    const int j = (nq * 4 + t3) * 16 + cbase;  // original column
#pragma unroll
    for (int mf = 0; mf < 2; ++mf) {
#pragma unroll
      for (int jr = 0; jr < 4; ++jr) {
        const int rl = wv * 32 + mf * 16 + kg * 4 + jr;
        const int gr = r0 + rl;
        if (gr < NN) {
          const size_t idx = (size_t)gr * HD + j;
          const float iv = sigmoidf_(acc[mf][3 * t3 + 0][jr] + bi);
          const float ov = sigmoidf_(acc[mf][3 * t3 + 1][jr] + bo);
          const float uv = tanhf_(acc[mf][3 * t3 + 2][jr] + bu);
          const float cn = iv * uv + outc[idx];
          out[idx] = ov * tanhf_(cn);
          outc[idx] = cn;
        }
      }
    }
  }
}

// ================= fallback path (R1 kernels, used when ws is too small) ======
__global__ __launch_bounds__(256) void edge_kernel(
    const float* __restrict__ h, const float* __restrict__ c,
    const unsigned short* __restrict__ Wfb, const float* __restrict__ Ufb,
    const int* __restrict__ esrc, const int* __restrict__ edst,
    float* h_tild, float* c_agg) {
  __shared__ __align__(16) unsigned short Als[64 * F_AS];
  __shared__ __align__(16) unsigned short Bls[256 * F_BS];
  __shared__ int srcl[64], dstl[64];

  const int tid = threadIdx.x;
  const int e0 = blockIdx.x * 64;
  if (tid < 64) { srcl[tid] = esrc[e0 + tid]; dstl[tid] = edst[e0 + tid]; }
  __syncthreads();

  const int lane = tid & 63;
  const int wv = tid >> 6;
  const int wm = wv >> 1, wn = wv & 1;
  const int cbase = lane & 15;
  const int kg = lane >> 4;

  f32x4 acc[2][8];
#pragma unroll
  for (int i = 0; i < 2; ++i)
#pragma unroll
    for (int j = 0; j < 8; ++j) acc[i][j] = {0.f, 0.f, 0.f, 0.f};

  const int arow = tid >> 2;
  const int acg = tid & 3;
  const float* hrow = h + (size_t)srcl[arow] * HD;
  float* htrow = h_tild + (size_t)dstl[arow] * HD;

  for (int kc = 0; kc < 4; ++kc) {
    const int k0 = kc * 64;
    const float4* s4 = (const float4*)(hrow + k0 + acg * 16);
    float4 q0 = s4[0], q1 = s4[1], q2 = s4[2], q3 = s4[3];
    short8 p0, p1;
    p0[0] = f2bf(q0.x); p0[1] = f2bf(q0.y); p0[2] = f2bf(q0.z); p0[3] = f2bf(q0.w);
    p0[4] = f2bf(q1.x); p0[5] = f2bf(q1.y); p0[6] = f2bf(q1.z); p0[7] = f2bf(q1.w);
    p1[0] = f2bf(q2.x); p1[1] = f2bf(q2.y); p1[2] = f2bf(q2.z); p1[3] = f2bf(q2.w);
    p1[4] = f2bf(q3.x); p1[5] = f2bf(q3.y); p1[6] = f2bf(q3.z); p1[7] = f2bf(q3.w);
    short8* ap = (short8*)&Als[arow * F_AS + acg * 16];
    ap[0] = p0; ap[1] = p1;
    {
      float* hp = htrow + k0 + acg * 16;
      atomAddF(hp + 0, q0.x);  atomAddF(hp + 1, q0.y);
      atomAddF(hp + 2, q0.z);  atomAddF(hp + 3, q0.w);
      atomAddF(hp + 4, q1.x);  atomAddF(hp + 5, q1.y);
      atomAddF(hp + 6, q1.z);  atomAddF(hp + 7, q1.w);
      atomAddF(hp + 8, q2.x);  atomAddF(hp + 9, q2.y);
      atomAddF(hp + 10, q2.z); atomAddF(hp + 11, q2.w);
      atomAddF(hp + 12, q3.x); atomAddF(hp + 13, q3.y);
      atomAddF(hp + 14, q3.z); atomAddF(hp + 15, q3.w);
    }
#pragma unroll
    for (int i = 0; i < 8; ++i) {
      int f = tid + 256 * i;
      int row = f >> 3, ch = f & 7;
      short8 vb = *(const short8*)(Wfb + row * 256 + k0 + ch * 8);
      *(short8*)&Bls[row * F_BS + ch * 8] = vb;
    }
    __syncthreads();
#pragma unroll
    for (int ks = 0; ks < 2; ++ks) {
      short8 a0 = *(const short8*)&Als[(wm * 32 + cbase) * F_AS + ks * 32 + kg * 8];
      short8 a1 = *(const short8*)&Als[(wm * 32 + 16 + cbase) * F_AS + ks * 32 + kg * 8];
#pragma unroll
      for (int nt = 0; nt < 8; ++nt) {
        short8 b = *(const short8*)&Bls[(wn * 128 + nt * 16 + cbase) * F_BS + ks * 32 + kg * 8];
        acc[0][nt] = __builtin_amdgcn_mfma_f32_16x16x32_bf16(a0, b, acc[0][nt], 0, 0, 0);
        acc[1][nt] = __builtin_amdgcn_mfma_f32_16x16x32_bf16(a1, b, acc[1][nt], 0, 0, 0);
      }
    }
    __syncthreads();
  }
  const int rsub = kg * 4;
#pragma unroll
  for (int nt = 0; nt < 8; ++nt) {
    const int coln = wn * 128 + nt * 16 + cbase;
    const float bias = Ufb[coln];
#pragma unroll
    for (int mt = 0; mt < 2; ++mt) {
#pragma unroll
      for (int j = 0; j < 4; ++j) {
        const int el = wm * 32 + mt * 16 + rsub + j;
        const float fg = sigmoidf_(acc[mt][nt][j] + bias);
        const float cv = c[(size_t)srcl[el] * HD + coln];
        atomAddF(c_agg + (size_t)dstl[el] * HD + coln, fg * cv);
      }
    }
  }
}

#define I_AS 40
#define I_BS 40

__global__ __launch_bounds__(256) void iou_kernel(
    const float* __restrict__ x, const unsigned short* __restrict__ Wioub,
    const unsigned short* __restrict__ Uioub, const float* __restrict__ bperm,
    float* out) {
  __shared__ __align__(16) unsigned short Als[32 * I_AS];
  __shared__ __align__(16) unsigned short Bls[768 * I_BS];

  const int tid = threadIdx.x;
  const int lane = tid & 63;
  const int wv = tid >> 6;
  const int wm = wv >> 1, wn = wv & 1;
  const int cbase = lane & 15;
  const int kg = lane >> 4;
  const int r0 = blockIdx.x * 32;

  float* h_tild = out;
  float* c_agg = out + (size_t)NN * HD;

  f32x4 acc[24];
#pragma unroll
  for (int t = 0; t < 24; ++t) acc[t] = {0.f, 0.f, 0.f, 0.f};

  const int arow = tid >> 3;
  const int acg = tid & 7;

  for (int pass = 0; pass < 2; ++pass) {
    const float* As = pass ? h_tild : x;
    const unsigned short* Bs = pass ? Uioub : Wioub;
    for (int kc = 0; kc < 8; ++kc) {
      const int k0 = kc * 32;
      float4 q = *(const float4*)(As + (size_t)(r0 + arow) * HD + k0 + acg * 4);
      short4v p;
      p[0] = f2bf(q.x); p[1] = f2bf(q.y); p[2] = f2bf(q.z); p[3] = f2bf(q.w);
      *(short4v*)&Als[arow * I_AS + acg * 4] = p;
#pragma unroll
      for (int i = 0; i < 12; ++i) {
        int f = tid + 256 * i;
        int row = f >> 2, ch = f & 3;
        short8 vb = *(const short8*)(Bs + row * 256 + k0 + ch * 8);
        *(short8*)&Bls[row * I_BS + ch * 8] = vb;
      }
      __syncthreads();
      short8 a = *(const short8*)&Als[(wm * 16 + cbase) * I_AS + kg * 8];
#pragma unroll
      for (int tt = 0; tt < 24; ++tt) {
        short8 b = *(const short8*)&Bls[((wn * 24 + tt) * 16 + cbase) * I_BS + kg * 8];
        acc[tt] = __builtin_amdgcn_mfma_f32_16x16x32_bf16(a, b, acc[tt], 0, 0, 0);
      }
      __syncthreads();
    }
  }
  const int rsub = kg * 4;
#pragma unroll
  for (int t3 = 0; t3 < 8; ++t3) {
    const int T = wn * 24 + 3 * t3;
    const float bi = bperm[(T + 0) * 16 + cbase];
    const float bo = bperm[(T + 1) * 16 + cbase];
    const float bu = bperm[(T + 2) * 16 + cbase];
    const int j = (wn * 8 + t3) * 16 + cbase;
#pragma unroll
    for (int jr = 0; jr < 4; ++jr) {
      const int r = r0 + wm * 16 + rsub + jr;
      const size_t idx = (size_t)r * HD + j;
      const float iv = sigmoidf_(acc[3 * t3 + 0][jr] + bi);
      const float ov = sigmoidf_(acc[3 * t3 + 1][jr] + bo);
      const float uv = tanhf_(acc[3 * t3 + 2][jr] + bu);
      const float cn = iv * uv + c_agg[idx];
      out[idx] = ov * tanhf_(cn);
      c_agg[idx] = cn;
    }
  }
}

extern "C" void kernel_launch(void* const* d_in, const int* in_sizes, int n_in,
                              void* d_out, int out_size, void* d_ws, size_t ws_size,
                              hipStream_t stream) {
  const float* x    = (const float*)d_in[0];
  const float* h    = (const float*)d_in[1];
  const float* c    = (const float*)d_in[2];
  const float* Wiou = (const float*)d_in[3];
  const float* Uiou = (const float*)d_in[4];
  const float* biou = (const float*)d_in[5];
  const float* Ufw  = (const float*)d_in[6];
  const float* Ufb  = (const float*)d_in[7];
  const int* esrc   = (const int*)d_in[8];
  const int* edst   = (const int*)d_in[9];
  float* out = (float*)d_out;

  char* ws = (char*)d_ws;
  unsigned short* Wfb   = (unsigned short*)(ws + OFF_WFB);
  unsigned short* Bp    = (unsigned short*)(ws + OFF_BP);
  float* bperm          = (float*)(ws + OFF_BPERM);

  if (ws_size >= WS_NEED) {
    int* rpp  = (int*)(ws + OFF_ROWPTR);
    int* nxt  = (int*)(ws + OFF_NEXT);
    int* slot = (int*)(ws + OFF_SLOT);
    int* psrc = (int*)(ws + OFF_PSRC);
    int* bsum = (int*)(ws + OFF_BSUM);
    char* zpage = ws + OFF_ZERO;
    unsigned short* fcb = (unsigned short*)(ws + OFF_FC);

    (void)hipMemsetAsync(nxt, 0, (size_t)NN * sizeof(int), stream);
    (void)hipMemsetAsync(zpage, 0, 1024, stream);
    prep_kernel<<<1795, 256, 0, stream>>>(Ufw, Wiou, Uiou, biou, Wfb, Bp, bperm);
    hist_kernel<<<(NE + 255) / 256, 256, 0, stream>>>(edst, nxt);
    scan_part<<<(NN + 1023) / 1024, 256, 0, stream>>>(nxt, rpp, bsum);
    scan_top<<<1, 256, 0, stream>>>(bsum, rpp, (NN + 1023) / 1024);
    scan_add<<<(NN + 1023) / 1024, 256, 0, stream>>>(rpp, bsum, nxt);
    scatter_kernel<<<(NE + 255) / 256, 256, 0, stream>>>(esrc, edst, nxt, slot, psrc);
    edge_fc_kernel<<<NE / 64, 256, 0, stream>>>(h, c, Wfb, Ufb, esrc, slot, fcb);
    gather_kernel<<<NN / 32, 256, 0, stream>>>(h, rpp, psrc, fcb, out + (size_t)NN * HD);
    const int rgrps = (NN + 127) / 128;
    iou_gemm4_kernel<<<rgrps * 4, 256, 0, stream>>>(x, Bp, bperm, rpp, fcb, zpage, out);
  } else {
    // fallback: R1 scatter-atomic path (row-major permuted weights in BP region)
    unsigned short* Wioub = (unsigned short*)(ws + OFF_BP);
    unsigned short* Uioub = (unsigned short*)(ws + OFF_BP + 393216);
    (void)hipMemsetAsync(d_out, 0, (size_t)out_size * sizeof(float), stream);
    prep_fb_kernel<<<1795, 256, 0, stream>>>(Ufw, Wiou, Uiou, biou, Wfb, Wioub, Uioub, bperm);
    edge_kernel<<<NE / 64, 256, 0, stream>>>(h, c, Wfb, Ufb, esrc, edst,
                                             out, out + (size_t)NN * HD);
    iou_kernel<<<NN / 32, 256, 0, stream>>>(x, Wioub, Uioub, bperm, out);
  }
}

// Round 9
// 835.241 us; speedup vs baseline: 1.3445x; 1.0422x over previous
//
#include <hip/hip_runtime.h>

#define NN 200000
#define NE 200000
#define HD 256

typedef __attribute__((ext_vector_type(8))) short short8;
typedef __attribute__((ext_vector_type(4))) short short4v;
typedef __attribute__((ext_vector_type(4))) float f32x4;
typedef __attribute__((ext_vector_type(4))) unsigned int u32x4;

static __device__ __forceinline__ unsigned short f2bf(float f) {
  unsigned u = __float_as_uint(f);
  u = (u + 0x7FFFu + ((u >> 16) & 1u)) >> 16;
  return (unsigned short)u;
}
static __device__ __forceinline__ float bf2f(unsigned short u) {
  return __uint_as_float(((unsigned)u) << 16);
}
static __device__ __forceinline__ float sigmoidf_(float x) {
  return 1.0f / (1.0f + __expf(-x));
}
static __device__ __forceinline__ float tanhf_(float x) {
  return 2.0f / (1.0f + __expf(-2.0f * x)) - 1.0f;
}
static __device__ __forceinline__ void atomAddF(float* p, float v) {
  __hip_atomic_fetch_add(p, v, __ATOMIC_RELAXED, __HIP_MEMORY_SCOPE_AGENT);
}
static __device__ __forceinline__ int atomAddI(int* p, int v) {
  return __hip_atomic_fetch_add(p, v, __ATOMIC_RELAXED, __HIP_MEMORY_SCOPE_AGENT);
}

#if defined(__HIP_DEVICE_COMPILE__)
static __device__ __forceinline__ void gload_lds16(const void* g, void* l) {
  __builtin_amdgcn_global_load_lds(
      (const __attribute__((address_space(1))) void*)g,
      (__attribute__((address_space(3))) void*)l, 16, 0, 0);
}
// pack_hi16(lo_f32bits, hi_f32bits): low16 = trunc-bf16(lo), high16 = trunc-bf16(hi)
static __device__ __forceinline__ unsigned pack_hi16(unsigned lo, unsigned hi) {
  return __builtin_amdgcn_perm(hi, lo, 0x07060302u);
}
#else
static __device__ __forceinline__ void gload_lds16(const void*, void*) {}
static __device__ __forceinline__ unsigned pack_hi16(unsigned lo, unsigned hi) {
  return (lo >> 16) | (hi & 0xffff0000u);
}
#endif

// ws layout (bytes)
#define OFF_WFB    0u           // bf16[256*256]
#define OFF_BP     131072u      // packed B fragments: bf16[16*48*64*8] = 786432 B
#define OFF_BPERM  917504u      // f32[768]
#define OFF_ROWPTR 920576u      // int[NN+1]
#define OFF_NEXT   1720832u     // int[NN]
#define OFF_SLOT   2520832u     // int[NE]
#define OFF_PSRC   3320832u     // int[NE]
#define OFF_BSUM   4120832u     // int[256]
#define OFF_ZERO   4121856u     // 1024 B of zeros
#define OFF_FC     4122880u     // bf16[NE*HD]
#define WS_NEED    106522880ull

// --------- prep (fast path): Wfb bf16; B fragment-packed; bias gate-permuted --
__global__ __launch_bounds__(256) void prep_kernel(
    const float* __restrict__ Ufw, const float* __restrict__ Wiou,
    const float* __restrict__ Uiou, const float* __restrict__ biou,
    unsigned short* __restrict__ Wfb, unsigned short* __restrict__ Bp,
    float* __restrict__ bperm) {
  int idx = blockIdx.x * 256 + threadIdx.x;
  if (idx < 65536) {
    Wfb[idx] = f2bf(Ufw[idx]);
  } else if (idx < 458752) {
    int o = idx - 65536;
    int kc = o / 24576;
    int rem = o - kc * 24576;
    int tt = rem / 512;
    int rem2 = rem - tt * 512;
    int ln = rem2 >> 3, e = rem2 & 7;
    int cc = ln & 15, kgp = ln >> 4;
    int kk = kc * 32 + kgp * 8 + e;
    int g = tt % 3, tj = tt / 3;
    int orow = g * 256 + tj * 16 + cc;
    float v = (kk < 256) ? Wiou[orow * 256 + kk] : Uiou[orow * 256 + (kk - 256)];
    Bp[o] = f2bf(v);
  } else if (idx < 459520) {
    int j2 = idx - 458752;
    int T = j2 >> 4, cc = j2 & 15;
    int g = T % 3, tj = T / 3;
    bperm[j2] = biou[g * 256 + tj * 16 + cc];
  }
}

// --------- prep (fallback): plain gate-permuted row-major W/U ---------------
__global__ __launch_bounds__(256) void prep_fb_kernel(
    const float* __restrict__ Ufw, const float* __restrict__ Wiou,
    const float* __restrict__ Uiou, const float* __restrict__ biou,
    unsigned short* __restrict__ Wfb, unsigned short* __restrict__ Wioub,
    unsigned short* __restrict__ Uioub, float* __restrict__ bperm) {
  int idx = blockIdx.x * 256 + threadIdx.x;
  if (idx < 65536) {
    Wfb[idx] = f2bf(Ufw[idx]);
  } else if (idx < 262144) {
    int i2 = idx - 65536;
    int rp = i2 >> 8, k = i2 & 255;
    int T = rp >> 4, cc = rp & 15;
    int g = T % 3, tj = T / 3;
    Wioub[i2] = f2bf(Wiou[(g * 256 + tj * 16 + cc) * 256 + k]);
  } else if (idx < 458752) {
    int i2 = idx - 262144;
    int rp = i2 >> 8, k = i2 & 255;
    int T = rp >> 4, cc = rp & 15;
    int g = T % 3, tj = T / 3;
    Uioub[i2] = f2bf(Uiou[(g * 256 + tj * 16 + cc) * 256 + k]);
  } else if (idx < 459520) {
    int j2 = idx - 458752;
    int T = j2 >> 4, cc = j2 & 15;
    int g = T % 3, tj = T / 3;
    bperm[j2] = biou[g * 256 + tj * 16 + cc];
  }
}

// ---------------- CSR build ----------------
__global__ __launch_bounds__(256) void hist_kernel(const int* __restrict__ edst,
                                                   int* __restrict__ cnt) {
  int e = blockIdx.x * 256 + threadIdx.x;
  if (e < NE) atomAddI(&cnt[edst[e]], 1);
}

__global__ __launch_bounds__(256) void scan_part(const int* __restrict__ cnt,
                                                 int* __restrict__ rp,
                                                 int* __restrict__ bsum) {
  __shared__ int sd[256];
  int t = threadIdx.x;
  int base = blockIdx.x * 1024 + t * 4;
  int v0 = (base + 0 < NN) ? cnt[base + 0] : 0;
  int v1 = (base + 1 < NN) ? cnt[base + 1] : 0;
  int v2 = (base + 2 < NN) ? cnt[base + 2] : 0;
  int v3 = (base + 3 < NN) ? cnt[base + 3] : 0;
  int s = v0 + v1 + v2 + v3;
  sd[t] = s;
  __syncthreads();
  for (int off = 1; off < 256; off <<= 1) {
    int add = (t >= off) ? sd[t - off] : 0;
    __syncthreads();
    sd[t] += add;
    __syncthreads();
  }
  int run = sd[t] - s;  // exclusive
  if (base + 0 < NN) rp[base + 0] = run; run += v0;
  if (base + 1 < NN) rp[base + 1] = run; run += v1;
  if (base + 2 < NN) rp[base + 2] = run; run += v2;
  if (base + 3 < NN) rp[base + 3] = run;
  if (t == 255) bsum[blockIdx.x] = sd[255];
}

__global__ __launch_bounds__(256) void scan_top(int* __restrict__ bsum,
                                                int* __restrict__ rp, int nb) {
  __shared__ int sd[256];
  int t = threadIdx.x;
  int v = (t < nb) ? bsum[t] : 0;
  sd[t] = v;
  __syncthreads();
  for (int off = 1; off < 256; off <<= 1) {
    int add = (t >= off) ? sd[t - off] : 0;
    __syncthreads();
    sd[t] += add;
    __syncthreads();
  }
  bsum[t] = sd[t] - v;  // exclusive block offsets
  if (t == 0) rp[NN] = NE;
}

__global__ __launch_bounds__(256) void scan_add(int* __restrict__ rp,
                                                const int* __restrict__ bsum,
                                                int* __restrict__ nxt) {
  int t = threadIdx.x;
  int base = blockIdx.x * 1024 + t * 4;
  int off = bsum[blockIdx.x];
#pragma unroll
  for (int j = 0; j < 4; ++j) {
    int i = base + j;
    if (i < NN) {
      int val = rp[i] + off;
      rp[i] = val;
      nxt[i] = val;
    }
  }
}

__global__ __launch_bounds__(256) void scatter_kernel(
    const int* __restrict__ esrc, const int* __restrict__ edst,
    int* __restrict__ nxt, int* __restrict__ slotArr, int* __restrict__ psrc) {
  int e = blockIdx.x * 256 + threadIdx.x;
  if (e < NE) {
    int d = edst[e];
    int pos = atomAddI(&nxt[d], 1);
    slotArr[e] = pos;
    psrc[pos] = esrc[e];
  }
}

// ---------------- edge kernel: fc[slot] = sigmoid(h[src]@Ufw^T+b)*c[src] ------
#define F_AS 72
#define F_BS 72

__global__ __launch_bounds__(256) void edge_fc_kernel(
    const float* __restrict__ h, const float* __restrict__ c,
    const unsigned short* __restrict__ Wfb, const float* __restrict__ Ufb,
    const int* __restrict__ esrc, const int* __restrict__ slotArr,
    unsigned short* __restrict__ fcb) {
  __shared__ __align__(16) unsigned short Als[64 * F_AS];
  __shared__ __align__(16) unsigned short Bls[256 * F_BS];
  __shared__ int srcl[64], slotl[64];

  const int tid = threadIdx.x;
  const int e0 = blockIdx.x * 64;
  if (tid < 64) { srcl[tid] = esrc[e0 + tid]; slotl[tid] = slotArr[e0 + tid]; }
  __syncthreads();

  const int lane = tid & 63;
  const int wv = tid >> 6;
  const int wm = wv >> 1, wn = wv & 1;
  const int cbase = lane & 15;
  const int kg = lane >> 4;

  f32x4 acc[2][8];
#pragma unroll
  for (int i = 0; i < 2; ++i)
#pragma unroll
    for (int j = 0; j < 8; ++j) acc[i][j] = {0.f, 0.f, 0.f, 0.f};

  const int arow = tid >> 2;
  const int acg = tid & 3;
  const float* hrow = h + (size_t)srcl[arow] * HD;

  for (int kc = 0; kc < 4; ++kc) {
    const int k0 = kc * 64;
    const float4* s4 = (const float4*)(hrow + k0 + acg * 16);
    float4 q0 = s4[0], q1 = s4[1], q2 = s4[2], q3 = s4[3];
    short8 p0, p1;
    p0[0] = f2bf(q0.x); p0[1] = f2bf(q0.y); p0[2] = f2bf(q0.z); p0[3] = f2bf(q0.w);
    p0[4] = f2bf(q1.x); p0[5] = f2bf(q1.y); p0[6] = f2bf(q1.z); p0[7] = f2bf(q1.w);
    p1[0] = f2bf(q2.x); p1[1] = f2bf(q2.y); p1[2] = f2bf(q2.z); p1[3] = f2bf(q2.w);
    p1[4] = f2bf(q3.x); p1[5] = f2bf(q3.y); p1[6] = f2bf(q3.z); p1[7] = f2bf(q3.w);
    short8* ap = (short8*)&Als[arow * F_AS + acg * 16];
    ap[0] = p0; ap[1] = p1;
#pragma unroll
    for (int i = 0; i < 8; ++i) {
      int f = tid + 256 * i;
      int row = f >> 3, ch = f & 7;
      short8 vb = *(const short8*)(Wfb + row * 256 + k0 + ch * 8);
      *(short8*)&Bls[row * F_BS + ch * 8] = vb;
    }
    __syncthreads();
#pragma unroll
    for (int ks = 0; ks < 2; ++ks) {
      short8 a0 = *(const short8*)&Als[(wm * 32 + cbase) * F_AS + ks * 32 + kg * 8];
      short8 a1 = *(const short8*)&Als[(wm * 32 + 16 + cbase) * F_AS + ks * 32 + kg * 8];
#pragma unroll
      for (int nt = 0; nt < 8; ++nt) {
        short8 b = *(const short8*)&Bls[(wn * 128 + nt * 16 + cbase) * F_BS + ks * 32 + kg * 8];
        acc[0][nt] = __builtin_amdgcn_mfma_f32_16x16x32_bf16(a0, b, acc[0][nt], 0, 0, 0);
        acc[1][nt] = __builtin_amdgcn_mfma_f32_16x16x32_bf16(a1, b, acc[1][nt], 0, 0, 0);
      }
    }
    __syncthreads();
  }
  const int rsub = kg * 4;
#pragma unroll
  for (int nt = 0; nt < 8; ++nt) {
    const int coln = wn * 128 + nt * 16 + cbase;
    const float bias = Ufb[coln];
#pragma unroll
    for (int mt = 0; mt < 2; ++mt) {
#pragma unroll
      for (int j = 0; j < 4; ++j) {
        const int el = wm * 32 + mt * 16 + rsub + j;
        const float fg = sigmoidf_(acc[mt][nt][j] + bias);
        const float cv = c[(size_t)srcl[el] * HD + coln];
        fcb[(size_t)slotl[el] * HD + coln] = f2bf(fg * cv);
      }
    }
  }
}

// ---------------- gather kernel: c_agg (f32 -> out c-half), h_tild (bf16 ->
// first-child slot of fcb; GEMM staging applies its own source-XOR) ----------
__global__ __launch_bounds__(256) void gather_kernel(
    const float* __restrict__ h, const int* __restrict__ rp,
    const int* __restrict__ psrc, unsigned short* __restrict__ fcb,
    float* __restrict__ cagg) {
  const int tid = threadIdx.x;
  const int node = blockIdx.x * 32 + (tid >> 3);
  const int cg = tid & 7;  // 32 cols per thread
  const int s0 = rp[node], s1 = rp[node + 1];

  float hs[32], cs[32];
#pragma unroll
  for (int q = 0; q < 32; ++q) { hs[q] = 0.f; cs[q] = 0.f; }

  for (int s = s0; s < s1; ++s) {
    const int src = psrc[s];
    const float4* hp = (const float4*)(h + (size_t)src * HD + cg * 32);
    const short8* fp = (const short8*)(fcb + (size_t)s * HD + cg * 32);
#pragma unroll
    for (int q = 0; q < 8; ++q) {
      float4 v = hp[q];
      hs[4 * q + 0] += v.x; hs[4 * q + 1] += v.y;
      hs[4 * q + 2] += v.z; hs[4 * q + 3] += v.w;
    }
#pragma unroll
    for (int q = 0; q < 4; ++q) {
      short8 w = fp[q];
#pragma unroll
      for (int e = 0; e < 8; ++e) cs[8 * q + e] += bf2f((unsigned short)w[e]);
    }
  }
  float4* cp = (float4*)(cagg + (size_t)node * HD + cg * 32);
#pragma unroll
  for (int q = 0; q < 8; ++q) {
    float4 v = {cs[4 * q + 0], cs[4 * q + 1], cs[4 * q + 2], cs[4 * q + 3]};
    cp[q] = v;
  }
  if (s1 > s0) {
    short8* hd = (short8*)(fcb + (size_t)s0 * HD + cg * 32);
#pragma unroll
    for (int q = 0; q < 4; ++q) {
      short8 p;
#pragma unroll
      for (int e = 0; e < 8; ++e) p[e] = f2bf(hs[8 * q + e]);
      hd[q] = p;
    }
  }
}

// ---------------- iou GEMM v5: 128 rows x 96 cols, 256 thr, BK=64 ------------
// 4 waves, wave = 32 rows x 96 cols: acc[2][6] = 48 AGPR; VGPR+AGPR <= 170 ->
// 3 waves/SIMD, 3 blocks/CU (LDS 44 KB). 8 k-steps (BK=64) -> 16 barriers.
// All staging via global_load_lds with source pre-swizzle; x->bf16 via
// v_perm_b32 truncating pack (1 op / 2 elems).
__global__ __launch_bounds__(256, 3) void iou_gemm5_kernel(
    const float* __restrict__ x, const unsigned short* __restrict__ Bp,
    const float* __restrict__ bperm, const int* __restrict__ rp,
    const unsigned short* __restrict__ fcb, const char* __restrict__ zpage,
    float* __restrict__ out) {
  __shared__ __align__(16) unsigned char Als[32768];  // x f32 tile / ht bf16 tile
  __shared__ __align__(16) unsigned char Bls[12288];  // 12 x 1024 B fragments

  const int tid = threadIdx.x;
  const int lane = tid & 63;
  const int wv = tid >> 6;
  const int cbase = lane & 15;
  const int kg = lane >> 4;

  const int bid = blockIdx.x;
  const int cg = bid & 7;          // column group: tiles [cg*6, cg*6+6)
  const int r0 = (bid >> 3) * 128;
  const bool full = (r0 + 128 <= NN);

  // x staging source (row = i*16 + (tid>>4); (row&7) == ((tid>>4)&7) for all i)
  const unsigned xswz = ((unsigned)(tid & 15) * 16) ^ ((((unsigned)(tid >> 4)) & 7) << 5);
  const char* xbase = (const char*)x + (size_t)(full ? (r0 + (tid >> 4)) : (NN - 1)) * 1024 + xswz;

  // ht staging sources (row = i*32 + (tid>>3); (row&7) == ((tid>>3)&7))
  const unsigned hswz = ((unsigned)(tid & 7) * 16) ^ ((((unsigned)(tid >> 3)) & 7) << 4);
  const char* hsrc[4];
#pragma unroll
  for (int i = 0; i < 4; ++i) {
    int rr = r0 + i * 32 + (tid >> 3);
    if (rr >= NN) rr = NN - 1;
    const int s0 = rp[rr], s1 = rp[rr + 1];
    const char* base = (s1 > s0) ? (const char*)(fcb + (size_t)s0 * HD) : zpage;
    hsrc[i] = base + hswz;
  }

  f32x4 acc[2][6];
#pragma unroll
  for (int m = 0; m < 2; ++m)
#pragma unroll
    for (int t = 0; t < 6; ++t) acc[m][t] = {0.f, 0.f, 0.f, 0.f};

  const int frow0 = wv * 32 + cbase;
  const unsigned swx = ((unsigned)(frow0 & 7)) << 5;
  const unsigned swh = ((unsigned)(frow0 & 7)) << 4;
  const unsigned char* ar0x = Als + frow0 * 256;
  const unsigned char* ar1x = Als + (frow0 + 16) * 256;
  const unsigned char* ar0h = Als + frow0 * 128;
  const unsigned char* ar1h = Als + (frow0 + 16) * 128;
  unsigned char* lA = Als + wv * 1024 + lane * 16;
  unsigned char* lB = Bls + wv * 1024 + lane * 16;
  const unsigned char* bread = Bls + lane * 16;

  // ---- phase 1: x @ W^T (kc = 0..3, f32 source) ----
  for (int kc = 0; kc < 4; ++kc) {
    // stage B: frags f = i*4+wv -> (kchunk=f/6, t=f%6)
#pragma unroll
    for (int i = 0; i < 3; ++i) {
      const int f = i * 4 + wv;
      const int kch = f / 6, t = f - kch * 6;
      gload_lds16((const char*)Bp + ((size_t)(kc * 2 + kch) * 48 + cg * 6 + t) * 1024 + lane * 16,
                  lB + i * 4096);
    }
    // stage A (x f32, 32 KB)
    if (full) {
#pragma unroll
      for (int i = 0; i < 8; ++i)
        gload_lds16(xbase + (size_t)i * 16384 + kc * 256, lA + i * 4096);
    } else {
#pragma unroll
      for (int i = 0; i < 8; ++i) {
        int rr = r0 + i * 16 + (tid >> 4);
        if (rr >= NN) rr = NN - 1;
        gload_lds16((const char*)x + (size_t)rr * 1024 + kc * 256 + xswz, lA + i * 4096);
      }
    }
    __syncthreads();
#pragma unroll
    for (int ks = 0; ks < 2; ++ks) {
      u32x4 q0 = *(const u32x4*)(ar0x + ((unsigned)(ks * 128 + kg * 32) ^ swx));
      u32x4 q1 = *(const u32x4*)(ar0x + ((unsigned)(ks * 128 + kg * 32 + 16) ^ swx));
      u32x4 q2 = *(const u32x4*)(ar1x + ((unsigned)(ks * 128 + kg * 32) ^ swx));
      u32x4 q3 = *(const u32x4*)(ar1x + ((unsigned)(ks * 128 + kg * 32 + 16) ^ swx));
      u32x4 p0, p1;
      p0[0] = pack_hi16(q0[0], q0[1]); p0[1] = pack_hi16(q0[2], q0[3]);
      p0[2] = pack_hi16(q1[0], q1[1]); p0[3] = pack_hi16(q1[2], q1[3]);
      p1[0] = pack_hi16(q2[0], q2[1]); p1[1] = pack_hi16(q2[2], q2[3]);
      p1[2] = pack_hi16(q3[0], q3[1]); p1[3] = pack_hi16(q3[2], q3[3]);
      short8 a0 = __builtin_bit_cast(short8, p0);
      short8 a1 = __builtin_bit_cast(short8, p1);
#pragma unroll
      for (int t = 0; t < 6; ++t) {
        short8 b = *(const short8*)(bread + (ks * 6 + t) * 1024);
        acc[0][t] = __builtin_amdgcn_mfma_f32_16x16x32_bf16(a0, b, acc[0][t], 0, 0, 0);
        acc[1][t] = __builtin_amdgcn_mfma_f32_16x16x32_bf16(a1, b, acc[1][t], 0, 0, 0);
      }
    }
    __syncthreads();
  }

  // ---- phase 2: h_tild @ U^T (kc = 4..7, bf16 source) ----
  for (int kc = 4; kc < 8; ++kc) {
#pragma unroll
    for (int i = 0; i < 3; ++i) {
      const int f = i * 4 + wv;
      const int kch = f / 6, t = f - kch * 6;
      gload_lds16((const char*)Bp + ((size_t)(kc * 2 + kch) * 48 + cg * 6 + t) * 1024 + lane * 16,
                  lB + i * 4096);
    }
    const int kcH = kc - 4;
#pragma unroll
    for (int i = 0; i < 4; ++i)
      gload_lds16(hsrc[i] + kcH * 128, lA + i * 4096);
    __syncthreads();
#pragma unroll
    for (int ks = 0; ks < 2; ++ks) {
      short8 a0 = *(const short8*)(ar0h + ((unsigned)(ks * 64 + kg * 16) ^ swh));
      short8 a1 = *(const short8*)(ar1h + ((unsigned)(ks * 64 + kg * 16) ^ swh));
#pragma unroll
      for (int t = 0; t < 6; ++t) {
        short8 b = *(const short8*)(bread + (ks * 6 + t) * 1024);
        acc[0][t] = __builtin_amdgcn_mfma_f32_16x16x32_bf16(a0, b, acc[0][t], 0, 0, 0);
        acc[1][t] = __builtin_amdgcn_mfma_f32_16x16x32_bf16(a1, b, acc[1][t], 0, 0, 0);
      }
    }
    __syncthreads();
  }

  // ---- epilogue: gate triples (i,o,u) = permuted tiles cg*6 + 3*t3 + g ----
  float* outc = out + (size_t)NN * HD;
#pragma unroll
  for (int t3 = 0; t3 < 2; ++t3) {
    const int TT = cg * 6 + 3 * t3;
    const float bi = bperm[(TT + 0) * 16 + cbase];
    const float bo = bperm[(TT + 1) * 16 + cbase];
    const float bu = bperm[(TT + 2) * 16 + cbase];
    const int j = (cg * 2 + t3) * 16 + cbase;  // original column
#pragma unroll
    for (int mf = 0; mf < 2; ++mf) {
#pragma unroll
      for (int jr = 0; jr < 4; ++jr) {
        const int gr = r0 + wv * 32 + mf * 16 + kg * 4 + jr;
        if (gr < NN) {
          const size_t idx = (size_t)gr * HD + j;
          const float iv = sigmoidf_(acc[mf][3 * t3 + 0][jr] + bi);
          const float ov = sigmoidf_(acc[mf][3 * t3 + 1][jr] + bo);
          const float uv = tanhf_(acc[mf][3 * t3 + 2][jr] + bu);
          const float cn = iv * uv + outc[idx];
          out[idx] = ov * tanhf_(cn);
          outc[idx] = cn;
        }
      }
    }
  }
}

// ================= fallback path (R1 kernels, used when ws is too small) ======
__global__ __launch_bounds__(256) void edge_kernel(
    const float* __restrict__ h, const float* __restrict__ c,
    const unsigned short* __restrict__ Wfb, const float* __restrict__ Ufb,
    const int* __restrict__ esrc, const int* __restrict__ edst,
    float* h_tild, float* c_agg) {
  __shared__ __align__(16) unsigned short Als[64 * F_AS];
  __shared__ __align__(16) unsigned short Bls[256 * F_BS];
  __shared__ int srcl[64], dstl[64];

  const int tid = threadIdx.x;
  const int e0 = blockIdx.x * 64;
  if (tid < 64) { srcl[tid] = esrc[e0 + tid]; dstl[tid] = edst[e0 + tid]; }
  __syncthreads();

  const int lane = tid & 63;
  const int wv = tid >> 6;
  const int wm = wv >> 1, wn = wv & 1;
  const int cbase = lane & 15;
  const int kg = lane >> 4;

  f32x4 acc[2][8];
#pragma unroll
  for (int i = 0; i < 2; ++i)
#pragma unroll
    for (int j = 0; j < 8; ++j) acc[i][j] = {0.f, 0.f, 0.f, 0.f};

  const int arow = tid >> 2;
  const int acg = tid & 3;
  const float* hrow = h + (size_t)srcl[arow] * HD;
  float* htrow = h_tild + (size_t)dstl[arow] * HD;

  for (int kc = 0; kc < 4; ++kc) {
    const int k0 = kc * 64;
    const float4* s4 = (const float4*)(hrow + k0 + acg * 16);
    float4 q0 = s4[0], q1 = s4[1], q2 = s4[2], q3 = s4[3];
    short8 p0, p1;
    p0[0] = f2bf(q0.x); p0[1] = f2bf(q0.y); p0[2] = f2bf(q0.z); p0[3] = f2bf(q0.w);
    p0[4] = f2bf(q1.x); p0[5] = f2bf(q1.y); p0[6] = f2bf(q1.z); p0[7] = f2bf(q1.w);
    p1[0] = f2bf(q2.x); p1[1] = f2bf(q2.y); p1[2] = f2bf(q2.z); p1[3] = f2bf(q2.w);
    p1[4] = f2bf(q3.x); p1[5] = f2bf(q3.y); p1[6] = f2bf(q3.z); p1[7] = f2bf(q3.w);
    short8* ap = (short8*)&Als[arow * F_AS + acg * 16];
    ap[0] = p0; ap[1] = p1;
    {
      float* hp = htrow + k0 + acg * 16;
      atomAddF(hp + 0, q0.x);  atomAddF(hp + 1, q0.y);
      atomAddF(hp + 2, q0.z);  atomAddF(hp + 3, q0.w);
      atomAddF(hp + 4, q1.x);  atomAddF(hp + 5, q1.y);
      atomAddF(hp + 6, q1.z);  atomAddF(hp + 7, q1.w);
      atomAddF(hp + 8, q2.x);  atomAddF(hp + 9, q2.y);
      atomAddF(hp + 10, q2.z); atomAddF(hp + 11, q2.w);
      atomAddF(hp + 12, q3.x); atomAddF(hp + 13, q3.y);
      atomAddF(hp + 14, q3.z); atomAddF(hp + 15, q3.w);
    }
#pragma unroll
    for (int i = 0; i < 8; ++i) {
      int f = tid + 256 * i;
      int row = f >> 3, ch = f & 7;
      short8 vb = *(const short8*)(Wfb + row * 256 + k0 + ch * 8);
      *(short8*)&Bls[row * F_BS + ch * 8] = vb;
    }
    __syncthreads();
#pragma unroll
    for (int ks = 0; ks < 2; ++ks) {
      short8 a0 = *(const short8*)&Als[(wm * 32 + cbase) * F_AS + ks * 32 + kg * 8];
      short8 a1 = *(const short8*)&Als[(wm * 32 + 16 + cbase) * F_AS + ks * 32 + kg * 8];
#pragma unroll
      for (int nt = 0; nt < 8; ++nt) {
        short8 b = *(const short8*)&Bls[(wn * 128 + nt * 16 + cbase) * F_BS + ks * 32 + kg * 8];
        acc[0][nt] = __builtin_amdgcn_mfma_f32_16x16x32_bf16(a0, b, acc[0][nt], 0, 0, 0);
        acc[1][nt] = __builtin_amdgcn_mfma_f32_16x16x32_bf16(a1, b, acc[1][nt], 0, 0, 0);
      }
    }
    __syncthreads();
  }
  const int rsub = kg * 4;
#pragma unroll
  for (int nt = 0; nt < 8; ++nt) {
    const int coln = wn * 128 + nt * 16 + cbase;
    const float bias = Ufb[coln];
#pragma unroll
    for (int mt = 0; mt < 2; ++mt) {
#pragma unroll
      for (int j = 0; j < 4; ++j) {
        const int el = wm * 32 + mt * 16 + rsub + j;
        const float fg = sigmoidf_(acc[mt][nt][j] + bias);
        const float cv = c[(size_t)srcl[el] * HD + coln];
        atomAddF(c_agg + (size_t)dstl[el] * HD + coln, fg * cv);
      }
    }
  }
}

#define I_AS 40
#define I_BS 40

__global__ __launch_bounds__(256) void iou_kernel(
    const float* __restrict__ x, const unsigned short* __restrict__ Wioub,
    const unsigned short* __restrict__ Uioub, const float* __restrict__ bperm,
    float* out) {
  __shared__ __align__(16) unsigned short Als[32 * I_AS];
  __shared__ __align__(16) unsigned short Bls[768 * I_BS];

  const int tid = threadIdx.x;
  const int lane = tid & 63;
  const int wv = tid >> 6;
  const int wm = wv >> 1, wn = wv & 1;
  const int cbase = lane & 15;
  const int kg = lane >> 4;
  const int r0 = blockIdx.x * 32;

  float* h_tild = out;
  float* c_agg = out + (size_t)NN * HD;

  f32x4 acc[24];
#pragma unroll
  for (int t = 0; t < 24; ++t) acc[t] = {0.f, 0.f, 0.f, 0.f};

  const int arow = tid >> 3;
  const int acg = tid & 7;

  for (int pass = 0; pass < 2; ++pass) {
    const float* As = pass ? h_tild : x;
    const unsigned short* Bs = pass ? Uioub : Wioub;
    for (int kc = 0; kc < 8; ++kc) {
      const int k0 = kc * 32;
      float4 q = *(const float4*)(As + (size_t)(r0 + arow) * HD + k0 + acg * 4);
      short4v p;
      p[0] = f2bf(q.x); p[1] = f2bf(q.y); p[2] = f2bf(q.z); p[3] = f2bf(q.w);
      *(short4v*)&Als[arow * I_AS + acg * 4] = p;
#pragma unroll
      for (int i = 0; i < 12; ++i) {
        int f = tid + 256 * i;
        int row = f >> 2, ch = f & 3;
        short8 vb = *(const short8*)(Bs + row * 256 + k0 + ch * 8);
        *(short8*)&Bls[row * I_BS + ch * 8] = vb;
      }
      __syncthreads();
      short8 a = *(const short8*)&Als[(wm * 16 + cbase) * I_AS + kg * 8];
#pragma unroll
      for (int tt = 0; tt < 24; ++tt) {
        short8 b = *(const short8*)&Bls[((wn * 24 + tt) * 16 + cbase) * I_BS + kg * 8];
        acc[tt] = __builtin_amdgcn_mfma_f32_16x16x32_bf16(a, b, acc[tt], 0, 0, 0);
      }
      __syncthreads();
    }
  }
  const int rsub = kg * 4;
#pragma unroll
  for (int t3 = 0; t3 < 8; ++t3) {
    const int T = wn * 24 + 3 * t3;
    const float bi = bperm[(T + 0) * 16 + cbase];
    const float bo = bperm[(T + 1) * 16 + cbase];
    const float bu = bperm[(T + 2) * 16 + cbase];
    const int j = (wn * 8 + t3) * 16 + cbase;
#pragma unroll
    for (int jr = 0; jr < 4; ++jr) {
      const int r = r0 + wm * 16 + rsub + jr;
      const size_t idx = (size_t)r * HD + j;
      const float iv = sigmoidf_(acc[3 * t3 + 0][jr] + bi);
      const float ov = sigmoidf_(acc[3 * t3 + 1][jr] + bo);
      const float uv = tanhf_(acc[3 * t3 + 2][jr] + bu);
      const float cn = iv * uv + c_agg[idx];
      out[idx] = ov * tanhf_(cn);
      c_agg[idx] = cn;
    }
  }
}

extern "C" void kernel_launch(void* const* d_in, const int* in_sizes, int n_in,
                              void* d_out, int out_size, void* d_ws, size_t ws_size,
                              hipStream_t stream) {
  const float* x    = (const float*)d_in[0];
  const float* h    = (const float*)d_in[1];
  const float* c    = (const float*)d_in[2];
  const float* Wiou = (const float*)d_in[3];
  const float* Uiou = (const float*)d_in[4];
  const float* biou = (const float*)d_in[5];
  const float* Ufw  = (const float*)d_in[6];
  const float* Ufb  = (const float*)d_in[7];
  const int* esrc   = (const int*)d_in[8];
  const int* edst   = (const int*)d_in[9];
  float* out = (float*)d_out;

  char* ws = (char*)d_ws;
  unsigned short* Wfb   = (unsigned short*)(ws + OFF_WFB);
  unsigned short* Bp    = (unsigned short*)(ws + OFF_BP);
  float* bperm          = (float*)(ws + OFF_BPERM);

  if (ws_size >= WS_NEED) {
    int* rpp  = (int*)(ws + OFF_ROWPTR);
    int* nxt  = (int*)(ws + OFF_NEXT);
    int* slot = (int*)(ws + OFF_SLOT);
    int* psrc = (int*)(ws + OFF_PSRC);
    int* bsum = (int*)(ws + OFF_BSUM);
    char* zpage = ws + OFF_ZERO;
    unsigned short* fcb = (unsigned short*)(ws + OFF_FC);

    (void)hipMemsetAsync(nxt, 0, (size_t)NN * sizeof(int), stream);
    (void)hipMemsetAsync(zpage, 0, 1024, stream);
    prep_kernel<<<1795, 256, 0, stream>>>(Ufw, Wiou, Uiou, biou, Wfb, Bp, bperm);
    hist_kernel<<<(NE + 255) / 256, 256, 0, stream>>>(edst, nxt);
    scan_part<<<(NN + 1023) / 1024, 256, 0, stream>>>(nxt, rpp, bsum);
    scan_top<<<1, 256, 0, stream>>>(bsum, rpp, (NN + 1023) / 1024);
    scan_add<<<(NN + 1023) / 1024, 256, 0, stream>>>(rpp, bsum, nxt);
    scatter_kernel<<<(NE + 255) / 256, 256, 0, stream>>>(esrc, edst, nxt, slot, psrc);
    edge_fc_kernel<<<NE / 64, 256, 0, stream>>>(h, c, Wfb, Ufb, esrc, slot, fcb);
    gather_kernel<<<NN / 32, 256, 0, stream>>>(h, rpp, psrc, fcb, out + (size_t)NN * HD);
    const int rgrps = (NN + 127) / 128;
    iou_gemm5_kernel<<<rgrps * 8, 256, 0, stream>>>(x, Bp, bperm, rpp, fcb, zpage, out);
  } else {
    // fallback: R1 scatter-atomic path (row-major permuted weights in BP region)
    unsigned short* Wioub = (unsigned short*)(ws + OFF_BP);
    unsigned short* Uioub = (unsigned short*)(ws + OFF_BP + 393216);
    (void)hipMemsetAsync(d_out, 0, (size_t)out_size * sizeof(float), stream);
    prep_fb_kernel<<<1795, 256, 0, stream>>>(Ufw, Wiou, Uiou, biou, Wfb, Wioub, Uioub, bperm);
    edge_kernel<<<NE / 64, 256, 0, stream>>>(h, c, Wfb, Ufb, esrc, edst,
                                             out, out + (size_t)NN * HD);
    iou_kernel<<<NN / 32, 256, 0, stream>>>(x, Wioub, Uioub, bperm, out);
  }
}

// Round 10
// 797.217 us; speedup vs baseline: 1.4087x; 1.0477x over previous
//
#include <hip/hip_runtime.h>

#define NN 200000
#define NE 200000
#define HD 256

typedef __attribute__((ext_vector_type(8))) short short8;
typedef __attribute__((ext_vector_type(4))) short short4v;
typedef __attribute__((ext_vector_type(4))) float f32x4;
typedef __attribute__((ext_vector_type(4))) unsigned int u32x4;

static __device__ __forceinline__ unsigned short f2bf(float f) {
  unsigned u = __float_as_uint(f);
  u = (u + 0x7FFFu + ((u >> 16) & 1u)) >> 16;
  return (unsigned short)u;
}
static __device__ __forceinline__ float bf2f(unsigned short u) {
  return __uint_as_float(((unsigned)u) << 16);
}
static __device__ __forceinline__ float sigmoidf_(float x) {
  return 1.0f / (1.0f + __expf(-x));
}
static __device__ __forceinline__ float tanhf_(float x) {
  return 2.0f / (1.0f + __expf(-2.0f * x)) - 1.0f;
}
static __device__ __forceinline__ void atomAddF(float* p, float v) {
  __hip_atomic_fetch_add(p, v, __ATOMIC_RELAXED, __HIP_MEMORY_SCOPE_AGENT);
}
static __device__ __forceinline__ int atomAddI(int* p, int v) {
  return __hip_atomic_fetch_add(p, v, __ATOMIC_RELAXED, __HIP_MEMORY_SCOPE_AGENT);
}

#if defined(__HIP_DEVICE_COMPILE__)
static __device__ __forceinline__ void gload_lds16(const void* g, void* l) {
  __builtin_amdgcn_global_load_lds(
      (const __attribute__((address_space(1))) void*)g,
      (__attribute__((address_space(3))) void*)l, 16, 0, 0);
}
static __device__ __forceinline__ unsigned pack_hi16(unsigned lo, unsigned hi) {
  return __builtin_amdgcn_perm(hi, lo, 0x07060302u);
}
#else
static __device__ __forceinline__ void gload_lds16(const void*, void*) {}
static __device__ __forceinline__ unsigned pack_hi16(unsigned lo, unsigned hi) {
  return (lo >> 16) | (hi & 0xffff0000u);
}
#endif

// ws layout (bytes)
#define OFF_WFB    0u           // bf16[256*256]
#define OFF_BP     131072u      // packed B fragments: bf16[16*48*64*8] = 786432 B
#define OFF_BPERM  917504u      // f32[768]
#define OFF_ROWPTR 920576u      // int[NN+1]
#define OFF_NEXT   1720832u     // int[NN]
#define OFF_SLOT   2520832u     // int[NE]
#define OFF_PSRC   3320832u     // int[NE]
#define OFF_BSUM   4120832u     // int[256]
#define OFF_ZERO   4121856u     // 1024 B of zeros
#define OFF_FC     4122880u     // bf16[NE*HD]
#define WS_NEED    106522880ull
#define OFF_XB     106522880ull // bf16[NN*HD] = 102400000 B
#define WS_NEED2   208922880ull

// --------- prep: Wfb bf16; B fragment-packed; bias gate-permuted --------------
__global__ __launch_bounds__(256) void prep_kernel(
    const float* __restrict__ Ufw, const float* __restrict__ Wiou,
    const float* __restrict__ Uiou, const float* __restrict__ biou,
    unsigned short* __restrict__ Wfb, unsigned short* __restrict__ Bp,
    float* __restrict__ bperm) {
  int idx = blockIdx.x * 256 + threadIdx.x;
  if (idx < 65536) {
    Wfb[idx] = f2bf(Ufw[idx]);
  } else if (idx < 458752) {
    int o = idx - 65536;
    int kc = o / 24576;
    int rem = o - kc * 24576;
    int tt = rem / 512;
    int rem2 = rem - tt * 512;
    int ln = rem2 >> 3, e = rem2 & 7;
    int cc = ln & 15, kgp = ln >> 4;
    int kk = kc * 32 + kgp * 8 + e;
    int g = tt % 3, tj = tt / 3;
    int orow = g * 256 + tj * 16 + cc;
    float v = (kk < 256) ? Wiou[orow * 256 + kk] : Uiou[orow * 256 + (kk - 256)];
    Bp[o] = f2bf(v);
  } else if (idx < 459520) {
    int j2 = idx - 458752;
    int T = j2 >> 4, cc = j2 & 15;
    int g = T % 3, tj = T / 3;
    bperm[j2] = biou[g * 256 + tj * 16 + cc];
  }
}

// --------- x -> bf16 pre-conversion (102 MB, L3-resident thereafter) ---------
__global__ __launch_bounds__(256) void xcvt_kernel(const float* __restrict__ x,
                                                   unsigned short* __restrict__ xb) {
  const size_t i = ((size_t)blockIdx.x * 256 + threadIdx.x) * 8;
  if (i < (size_t)NN * HD) {
    float4 a = *(const float4*)(x + i);
    float4 b = *(const float4*)(x + i + 4);
    short8 p;
    p[0] = f2bf(a.x); p[1] = f2bf(a.y); p[2] = f2bf(a.z); p[3] = f2bf(a.w);
    p[4] = f2bf(b.x); p[5] = f2bf(b.y); p[6] = f2bf(b.z); p[7] = f2bf(b.w);
    *(short8*)(xb + i) = p;
  }
}

// --------- prep (fallback): plain gate-permuted row-major W/U ---------------
__global__ __launch_bounds__(256) void prep_fb_kernel(
    const float* __restrict__ Ufw, const float* __restrict__ Wiou,
    const float* __restrict__ Uiou, const float* __restrict__ biou,
    unsigned short* __restrict__ Wfb, unsigned short* __restrict__ Wioub,
    unsigned short* __restrict__ Uioub, float* __restrict__ bperm) {
  int idx = blockIdx.x * 256 + threadIdx.x;
  if (idx < 65536) {
    Wfb[idx] = f2bf(Ufw[idx]);
  } else if (idx < 262144) {
    int i2 = idx - 65536;
    int rp = i2 >> 8, k = i2 & 255;
    int T = rp >> 4, cc = rp & 15;
    int g = T % 3, tj = T / 3;
    Wioub[i2] = f2bf(Wiou[(g * 256 + tj * 16 + cc) * 256 + k]);
  } else if (idx < 458752) {
    int i2 = idx - 262144;
    int rp = i2 >> 8, k = i2 & 255;
    int T = rp >> 4, cc = rp & 15;
    int g = T % 3, tj = T / 3;
    Uioub[i2] = f2bf(Uiou[(g * 256 + tj * 16 + cc) * 256 + k]);
  } else if (idx < 459520) {
    int j2 = idx - 458752;
    int T = j2 >> 4, cc = j2 & 15;
    int g = T % 3, tj = T / 3;
    bperm[j2] = biou[g * 256 + tj * 16 + cc];
  }
}

// ---------------- CSR build ----------------
__global__ __launch_bounds__(256) void hist_kernel(const int* __restrict__ edst,
                                                   int* __restrict__ cnt) {
  int e = blockIdx.x * 256 + threadIdx.x;
  if (e < NE) atomAddI(&cnt[edst[e]], 1);
}

__global__ __launch_bounds__(256) void scan_part(const int* __restrict__ cnt,
                                                 int* __restrict__ rp,
                                                 int* __restrict__ bsum) {
  __shared__ int sd[256];
  int t = threadIdx.x;
  int base = blockIdx.x * 1024 + t * 4;
  int v0 = (base + 0 < NN) ? cnt[base + 0] : 0;
  int v1 = (base + 1 < NN) ? cnt[base + 1] : 0;
  int v2 = (base + 2 < NN) ? cnt[base + 2] : 0;
  int v3 = (base + 3 < NN) ? cnt[base + 3] : 0;
  int s = v0 + v1 + v2 + v3;
  sd[t] = s;
  __syncthreads();
  for (int off = 1; off < 256; off <<= 1) {
    int add = (t >= off) ? sd[t - off] : 0;
    __syncthreads();
    sd[t] += add;
    __syncthreads();
  }
  int run = sd[t] - s;  // exclusive
  if (base + 0 < NN) rp[base + 0] = run; run += v0;
  if (base + 1 < NN) rp[base + 1] = run; run += v1;
  if (base + 2 < NN) rp[base + 2] = run; run += v2;
  if (base + 3 < NN) rp[base + 3] = run;
  if (t == 255) bsum[blockIdx.x] = sd[255];
}

__global__ __launch_bounds__(256) void scan_top(int* __restrict__ bsum,
                                                int* __restrict__ rp, int nb) {
  __shared__ int sd[256];
  int t = threadIdx.x;
  int v = (t < nb) ? bsum[t] : 0;
  sd[t] = v;
  __syncthreads();
  for (int off = 1; off < 256; off <<= 1) {
    int add = (t >= off) ? sd[t - off] : 0;
    __syncthreads();
    sd[t] += add;
    __syncthreads();
  }
  bsum[t] = sd[t] - v;  // exclusive block offsets
  if (t == 0) rp[NN] = NE;
}

__global__ __launch_bounds__(256) void scan_add(int* __restrict__ rp,
                                                const int* __restrict__ bsum,
                                                int* __restrict__ nxt) {
  int t = threadIdx.x;
  int base = blockIdx.x * 1024 + t * 4;
  int off = bsum[blockIdx.x];
#pragma unroll
  for (int j = 0; j < 4; ++j) {
    int i = base + j;
    if (i < NN) {
      int val = rp[i] + off;
      rp[i] = val;
      nxt[i] = val;
    }
  }
}

__global__ __launch_bounds__(256) void scatter_kernel(
    const int* __restrict__ esrc, const int* __restrict__ edst,
    int* __restrict__ nxt, int* __restrict__ slotArr, int* __restrict__ psrc) {
  int e = blockIdx.x * 256 + threadIdx.x;
  if (e < NE) {
    int d = edst[e];
    int pos = atomAddI(&nxt[d], 1);
    slotArr[e] = pos;
    psrc[pos] = esrc[e];
  }
}

// ---------------- edge kernel: fc[slot] = sigmoid(h[src]@Ufw^T+b)*c[src] ------
#define F_AS 72
#define F_BS 72

__global__ __launch_bounds__(256) void edge_fc_kernel(
    const float* __restrict__ h, const float* __restrict__ c,
    const unsigned short* __restrict__ Wfb, const float* __restrict__ Ufb,
    const int* __restrict__ esrc, const int* __restrict__ slotArr,
    unsigned short* __restrict__ fcb) {
  __shared__ __align__(16) unsigned short Als[64 * F_AS];
  __shared__ __align__(16) unsigned short Bls[256 * F_BS];
  __shared__ int srcl[64], slotl[64];

  const int tid = threadIdx.x;
  const int e0 = blockIdx.x * 64;
  if (tid < 64) { srcl[tid] = esrc[e0 + tid]; slotl[tid] = slotArr[e0 + tid]; }
  __syncthreads();

  const int lane = tid & 63;
  const int wv = tid >> 6;
  const int wm = wv >> 1, wn = wv & 1;
  const int cbase = lane & 15;
  const int kg = lane >> 4;

  f32x4 acc[2][8];
#pragma unroll
  for (int i = 0; i < 2; ++i)
#pragma unroll
    for (int j = 0; j < 8; ++j) acc[i][j] = {0.f, 0.f, 0.f, 0.f};

  const int arow = tid >> 2;
  const int acg = tid & 3;
  const float* hrow = h + (size_t)srcl[arow] * HD;

  for (int kc = 0; kc < 4; ++kc) {
    const int k0 = kc * 64;
    const float4* s4 = (const float4*)(hrow + k0 + acg * 16);
    float4 q0 = s4[0], q1 = s4[1], q2 = s4[2], q3 = s4[3];
    short8 p0, p1;
    p0[0] = f2bf(q0.x); p0[1] = f2bf(q0.y); p0[2] = f2bf(q0.z); p0[3] = f2bf(q0.w);
    p0[4] = f2bf(q1.x); p0[5] = f2bf(q1.y); p0[6] = f2bf(q1.z); p0[7] = f2bf(q1.w);
    p1[0] = f2bf(q2.x); p1[1] = f2bf(q2.y); p1[2] = f2bf(q2.z); p1[3] = f2bf(q2.w);
    p1[4] = f2bf(q3.x); p1[5] = f2bf(q3.y); p1[6] = f2bf(q3.z); p1[7] = f2bf(q3.w);
    short8* ap = (short8*)&Als[arow * F_AS + acg * 16];
    ap[0] = p0; ap[1] = p1;
#pragma unroll
    for (int i = 0; i < 8; ++i) {
      int f = tid + 256 * i;
      int row = f >> 3, ch = f & 7;
      short8 vb = *(const short8*)(Wfb + row * 256 + k0 + ch * 8);
      *(short8*)&Bls[row * F_BS + ch * 8] = vb;
    }
    __syncthreads();
#pragma unroll
    for (int ks = 0; ks < 2; ++ks) {
      short8 a0 = *(const short8*)&Als[(wm * 32 + cbase) * F_AS + ks * 32 + kg * 8];
      short8 a1 = *(const short8*)&Als[(wm * 32 + 16 + cbase) * F_AS + ks * 32 + kg * 8];
#pragma unroll
      for (int nt = 0; nt < 8; ++nt) {
        short8 b = *(const short8*)&Bls[(wn * 128 + nt * 16 + cbase) * F_BS + ks * 32 + kg * 8];
        acc[0][nt] = __builtin_amdgcn_mfma_f32_16x16x32_bf16(a0, b, acc[0][nt], 0, 0, 0);
        acc[1][nt] = __builtin_amdgcn_mfma_f32_16x16x32_bf16(a1, b, acc[1][nt], 0, 0, 0);
      }
    }
    __syncthreads();
  }
  const int rsub = kg * 4;
#pragma unroll
  for (int nt = 0; nt < 8; ++nt) {
    const int coln = wn * 128 + nt * 16 + cbase;
    const float bias = Ufb[coln];
#pragma unroll
    for (int mt = 0; mt < 2; ++mt) {
#pragma unroll
      for (int j = 0; j < 4; ++j) {
        const int el = wm * 32 + mt * 16 + rsub + j;
        const float fg = sigmoidf_(acc[mt][nt][j] + bias);
        const float cv = c[(size_t)srcl[el] * HD + coln];
        fcb[(size_t)slotl[el] * HD + coln] = f2bf(fg * cv);
      }
    }
  }
}

// ---------------- gather kernel: c_agg (f32 -> out c-half), h_tild (bf16 ->
// first-child slot of fcb; GEMM staging applies its own source-XOR) ----------
__global__ __launch_bounds__(256) void gather_kernel(
    const float* __restrict__ h, const int* __restrict__ rp,
    const int* __restrict__ psrc, unsigned short* __restrict__ fcb,
    float* __restrict__ cagg) {
  const int tid = threadIdx.x;
  const int node = blockIdx.x * 32 + (tid >> 3);
  const int cg = tid & 7;  // 32 cols per thread
  const int s0 = rp[node], s1 = rp[node + 1];

  float hs[32], cs[32];
#pragma unroll
  for (int q = 0; q < 32; ++q) { hs[q] = 0.f; cs[q] = 0.f; }

  for (int s = s0; s < s1; ++s) {
    const int src = psrc[s];
    const float4* hp = (const float4*)(h + (size_t)src * HD + cg * 32);
    const short8* fp = (const short8*)(fcb + (size_t)s * HD + cg * 32);
#pragma unroll
    for (int q = 0; q < 8; ++q) {
      float4 v = hp[q];
      hs[4 * q + 0] += v.x; hs[4 * q + 1] += v.y;
      hs[4 * q + 2] += v.z; hs[4 * q + 3] += v.w;
    }
#pragma unroll
    for (int q = 0; q < 4; ++q) {
      short8 w = fp[q];
#pragma unroll
      for (int e = 0; e < 8; ++e) cs[8 * q + e] += bf2f((unsigned short)w[e]);
    }
  }
  float4* cp = (float4*)(cagg + (size_t)node * HD + cg * 32);
#pragma unroll
  for (int q = 0; q < 8; ++q) {
    float4 v = {cs[4 * q + 0], cs[4 * q + 1], cs[4 * q + 2], cs[4 * q + 3]};
    cp[q] = v;
  }
  if (s1 > s0) {
    short8* hd = (short8*)(fcb + (size_t)s0 * HD + cg * 32);
#pragma unroll
    for (int q = 0; q < 4; ++q) {
      short8 p;
#pragma unroll
      for (int e = 0; e < 8; ++e) p[e] = f2bf(hs[8 * q + e]);
      hd[q] = p;
    }
  }
}

// ---------------- iou GEMM v6: all-bf16 A, 128 rows x 96 cols, BK=64 ----------
// Both phases stage 16 KB bf16 A-tiles via global_load_lds with source pre-XOR;
// no in-loop f32->bf16 pack. LDS 28 KB, acc[2][6]=48 AGPR -> (256,4): 4 blk/CU.
__global__ __launch_bounds__(256, 4) void iou_gemm6_kernel(
    const unsigned short* __restrict__ xb, const unsigned short* __restrict__ Bp,
    const float* __restrict__ bperm, const int* __restrict__ rp,
    const unsigned short* __restrict__ fcb, const char* __restrict__ zpage,
    float* __restrict__ out) {
  __shared__ __align__(16) unsigned char Als[16384];  // bf16 tile [128][128B]
  __shared__ __align__(16) unsigned char Bls[12288];  // 12 x 1024 B fragments

  const int tid = threadIdx.x;
  const int lane = tid & 63;
  const int wv = tid >> 6;
  const int cbase = lane & 15;
  const int kg = lane >> 4;

  const int bid = blockIdx.x;
  const int cg = bid & 7;          // column group: permuted tiles [cg*6, cg*6+6)
  const int r0 = (bid >> 3) * 128;

  // staging sources: row = i*32 + (tid>>3), 16B col seg = tid&7, row = 512 B
  const unsigned hswz = ((unsigned)(tid & 7) * 16) ^ ((((unsigned)(tid >> 3)) & 7) << 4);
  const char* xsrc[4];
  const char* hsrc[4];
#pragma unroll
  for (int i = 0; i < 4; ++i) {
    int rr = r0 + i * 32 + (tid >> 3);
    if (rr >= NN) rr = NN - 1;
    xsrc[i] = (const char*)xb + (size_t)rr * 512 + hswz;
    const int s0 = rp[rr], s1 = rp[rr + 1];
    const char* base = (s1 > s0) ? (const char*)(fcb + (size_t)s0 * HD) : zpage;
    hsrc[i] = base + hswz;
  }

  f32x4 acc[2][6];
#pragma unroll
  for (int m = 0; m < 2; ++m)
#pragma unroll
    for (int t = 0; t < 6; ++t) acc[m][t] = {0.f, 0.f, 0.f, 0.f};

  const int frow0 = wv * 32 + cbase;
  const unsigned swh = ((unsigned)(frow0 & 7)) << 4;
  const unsigned char* ar0 = Als + frow0 * 128;
  const unsigned char* ar1 = Als + (frow0 + 16) * 128;
  unsigned char* lA = Als + wv * 1024 + lane * 16;
  unsigned char* lB = Bls + wv * 1024 + lane * 16;
  const unsigned char* bread = Bls + lane * 16;

  for (int kc = 0; kc < 8; ++kc) {
    // stage B: fragment f = i*4+wv = kch*6+t for k-chunks (kc*2+kch)
#pragma unroll
    for (int i = 0; i < 3; ++i) {
      const int f = i * 4 + wv;
      const int kch = f / 6, t = f - kch * 6;
      gload_lds16((const char*)Bp + ((size_t)(kc * 2 + kch) * 48 + cg * 6 + t) * 1024 + lane * 16,
                  lB + i * 4096);
    }
    // stage A (16 KB bf16)
    if (kc < 4) {
      const int ko = kc * 128;
#pragma unroll
      for (int i = 0; i < 4; ++i) gload_lds16(xsrc[i] + ko, lA + i * 4096);
    } else {
      const int ko = (kc - 4) * 128;
#pragma unroll
      for (int i = 0; i < 4; ++i) gload_lds16(hsrc[i] + ko, lA + i * 4096);
    }
    __syncthreads();
#pragma unroll
    for (int ks = 0; ks < 2; ++ks) {
      short8 a0 = *(const short8*)(ar0 + ((unsigned)(ks * 64 + kg * 16) ^ swh));
      short8 a1 = *(const short8*)(ar1 + ((unsigned)(ks * 64 + kg * 16) ^ swh));
#pragma unroll
      for (int t = 0; t < 6; ++t) {
        short8 b = *(const short8*)(bread + (ks * 6 + t) * 1024);
        acc[0][t] = __builtin_amdgcn_mfma_f32_16x16x32_bf16(a0, b, acc[0][t], 0, 0, 0);
        acc[1][t] = __builtin_amdgcn_mfma_f32_16x16x32_bf16(a1, b, acc[1][t], 0, 0, 0);
      }
    }
    __syncthreads();
  }

  // epilogue: gate triples (i,o,u) = permuted tiles cg*6 + 3*t3 + g
  float* outc = out + (size_t)NN * HD;
#pragma unroll
  for (int t3 = 0; t3 < 2; ++t3) {
    const int TT = cg * 6 + 3 * t3;
    const float bi = bperm[(TT + 0) * 16 + cbase];
    const float bo = bperm[(TT + 1) * 16 + cbase];
    const float bu = bperm[(TT + 2) * 16 + cbase];
    const int j = (cg * 2 + t3) * 16 + cbase;  // original column
#pragma unroll
    for (int mf = 0; mf < 2; ++mf) {
#pragma unroll
      for (int jr = 0; jr < 4; ++jr) {
        const int gr = r0 + wv * 32 + mf * 16 + kg * 4 + jr;
        if (gr < NN) {
          const size_t idx = (size_t)gr * HD + j;
          const float iv = sigmoidf_(acc[mf][3 * t3 + 0][jr] + bi);
          const float ov = sigmoidf_(acc[mf][3 * t3 + 1][jr] + bo);
          const float uv = tanhf_(acc[mf][3 * t3 + 2][jr] + bu);
          const float cn = iv * uv + outc[idx];
          out[idx] = ov * tanhf_(cn);
          outc[idx] = cn;
        }
      }
    }
  }
}

// ---------------- iou GEMM v5 (mid tier, R9-proven): f32 x staging ------------
__global__ __launch_bounds__(256, 3) void iou_gemm5_kernel(
    const float* __restrict__ x, const unsigned short* __restrict__ Bp,
    const float* __restrict__ bperm, const int* __restrict__ rp,
    const unsigned short* __restrict__ fcb, const char* __restrict__ zpage,
    float* __restrict__ out) {
  __shared__ __align__(16) unsigned char Als[32768];
  __shared__ __align__(16) unsigned char Bls[12288];

  const int tid = threadIdx.x;
  const int lane = tid & 63;
  const int wv = tid >> 6;
  const int cbase = lane & 15;
  const int kg = lane >> 4;

  const int bid = blockIdx.x;
  const int cg = bid & 7;
  const int r0 = (bid >> 3) * 128;
  const bool full = (r0 + 128 <= NN);

  const unsigned xswz = ((unsigned)(tid & 15) * 16) ^ ((((unsigned)(tid >> 4)) & 7) << 5);
  const char* xbase = (const char*)x + (size_t)(full ? (r0 + (tid >> 4)) : (NN - 1)) * 1024 + xswz;

  const unsigned hswz = ((unsigned)(tid & 7) * 16) ^ ((((unsigned)(tid >> 3)) & 7) << 4);
  const char* hsrc[4];
#pragma unroll
  for (int i = 0; i < 4; ++i) {
    int rr = r0 + i * 32 + (tid >> 3);
    if (rr >= NN) rr = NN - 1;
    const int s0 = rp[rr], s1 = rp[rr + 1];
    const char* base = (s1 > s0) ? (const char*)(fcb + (size_t)s0 * HD) : zpage;
    hsrc[i] = base + hswz;
  }

  f32x4 acc[2][6];
#pragma unroll
  for (int m = 0; m < 2; ++m)
#pragma unroll
    for (int t = 0; t < 6; ++t) acc[m][t] = {0.f, 0.f, 0.f, 0.f};

  const int frow0 = wv * 32 + cbase;
  const unsigned swx = ((unsigned)(frow0 & 7)) << 5;
  const unsigned swh = ((unsigned)(frow0 & 7)) << 4;
  const unsigned char* ar0x = Als + frow0 * 256;
  const unsigned char* ar1x = Als + (frow0 + 16) * 256;
  const unsigned char* ar0h = Als + frow0 * 128;
  const unsigned char* ar1h = Als + (frow0 + 16) * 128;
  unsigned char* lA = Als + wv * 1024 + lane * 16;
  unsigned char* lB = Bls + wv * 1024 + lane * 16;
  const unsigned char* bread = Bls + lane * 16;

  for (int kc = 0; kc < 4; ++kc) {
#pragma unroll
    for (int i = 0; i < 3; ++i) {
      const int f = i * 4 + wv;
      const int kch = f / 6, t = f - kch * 6;
      gload_lds16((const char*)Bp + ((size_t)(kc * 2 + kch) * 48 + cg * 6 + t) * 1024 + lane * 16,
                  lB + i * 4096);
    }
    if (full) {
#pragma unroll
      for (int i = 0; i < 8; ++i)
        gload_lds16(xbase + (size_t)i * 16384 + kc * 256, lA + i * 4096);
    } else {
#pragma unroll
      for (int i = 0; i < 8; ++i) {
        int rr = r0 + i * 16 + (tid >> 4);
        if (rr >= NN) rr = NN - 1;
        gload_lds16((const char*)x + (size_t)rr * 1024 + kc * 256 + xswz, lA + i * 4096);
      }
    }
    __syncthreads();
#pragma unroll
    for (int ks = 0; ks < 2; ++ks) {
      u32x4 q0 = *(const u32x4*)(ar0x + ((unsigned)(ks * 128 + kg * 32) ^ swx));
      u32x4 q1 = *(const u32x4*)(ar0x + ((unsigned)(ks * 128 + kg * 32 + 16) ^ swx));
      u32x4 q2 = *(const u32x4*)(ar1x + ((unsigned)(ks * 128 + kg * 32) ^ swx));
      u32x4 q3 = *(const u32x4*)(ar1x + ((unsigned)(ks * 128 + kg * 32 + 16) ^ swx));
      u32x4 p0, p1;
      p0[0] = pack_hi16(q0[0], q0[1]); p0[1] = pack_hi16(q0[2], q0[3]);
      p0[2] = pack_hi16(q1[0], q1[1]); p0[3] = pack_hi16(q1[2], q1[3]);
      p1[0] = pack_hi16(q2[0], q2[1]); p1[1] = pack_hi16(q2[2], q2[3]);
      p1[2] = pack_hi16(q3[0], q3[1]); p1[3] = pack_hi16(q3[2], q3[3]);
      short8 a0 = __builtin_bit_cast(short8, p0);
      short8 a1 = __builtin_bit_cast(short8, p1);
#pragma unroll
      for (int t = 0; t < 6; ++t) {
        short8 b = *(const short8*)(bread + (ks * 6 + t) * 1024);
        acc[0][t] = __builtin_amdgcn_mfma_f32_16x16x32_bf16(a0, b, acc[0][t], 0, 0, 0);
        acc[1][t] = __builtin_amdgcn_mfma_f32_16x16x32_bf16(a1, b, acc[1][t], 0, 0, 0);
      }
    }
    __syncthreads();
  }

  for (int kc = 4; kc < 8; ++kc) {
#pragma unroll
    for (int i = 0; i < 3; ++i) {
      const int f = i * 4 + wv;
      const int kch = f / 6, t = f - kch * 6;
      gload_lds16((const char*)Bp + ((size_t)(kc * 2 + kch) * 48 + cg * 6 + t) * 1024 + lane * 16,
                  lB + i * 4096);
    }
    const int kcH = kc - 4;
#pragma unroll
    for (int i = 0; i < 4; ++i)
      gload_lds16(hsrc[i] + kcH * 128, lA + i * 4096);
    __syncthreads();
#pragma unroll
    for (int ks = 0; ks < 2; ++ks) {
      short8 a0 = *(const short8*)(ar0h + ((unsigned)(ks * 64 + kg * 16) ^ swh));
      short8 a1 = *(const short8*)(ar1h + ((unsigned)(ks * 64 + kg * 16) ^ swh));
#pragma unroll
      for (int t = 0; t < 6; ++t) {
        short8 b = *(const short8*)(bread + (ks * 6 + t) * 1024);
        acc[0][t] = __builtin_amdgcn_mfma_f32_16x16x32_bf16(a0, b, acc[0][t], 0, 0, 0);
        acc[1][t] = __builtin_amdgcn_mfma_f32_16x16x32_bf16(a1, b, acc[1][t], 0, 0, 0);
      }
    }
    __syncthreads();
  }

  float* outc = out + (size_t)NN * HD;
#pragma unroll
  for (int t3 = 0; t3 < 2; ++t3) {
    const int TT = cg * 6 + 3 * t3;
    const float bi = bperm[(TT + 0) * 16 + cbase];
    const float bo = bperm[(TT + 1) * 16 + cbase];
    const float bu = bperm[(TT + 2) * 16 + cbase];
    const int j = (cg * 2 + t3) * 16 + cbase;
#pragma unroll
    for (int mf = 0; mf < 2; ++mf) {
#pragma unroll
      for (int jr = 0; jr < 4; ++jr) {
        const int gr = r0 + wv * 32 + mf * 16 + kg * 4 + jr;
        if (gr < NN) {
          const size_t idx = (size_t)gr * HD + j;
          const float iv = sigmoidf_(acc[mf][3 * t3 + 0][jr] + bi);
          const float ov = sigmoidf_(acc[mf][3 * t3 + 1][jr] + bo);
          const float uv = tanhf_(acc[mf][3 * t3 + 2][jr] + bu);
          const float cn = iv * uv + outc[idx];
          out[idx] = ov * tanhf_(cn);
          outc[idx] = cn;
        }
      }
    }
  }
}

// ================= fallback path (R1 kernels, used when ws is too small) ======
__global__ __launch_bounds__(256) void edge_kernel(
    const float* __restrict__ h, const float* __restrict__ c,
    const unsigned short* __restrict__ Wfb, const float* __restrict__ Ufb,
    const int* __restrict__ esrc, const int* __restrict__ edst,
    float* h_tild, float* c_agg) {
  __shared__ __align__(16) unsigned short Als[64 * F_AS];
  __shared__ __align__(16) unsigned short Bls[256 * F_BS];
  __shared__ int srcl[64], dstl[64];

  const int tid = threadIdx.x;
  const int e0 = blockIdx.x * 64;
  if (tid < 64) { srcl[tid] = esrc[e0 + tid]; dstl[tid] = edst[e0 + tid]; }
  __syncthreads();

  const int lane = tid & 63;
  const int wv = tid >> 6;
  const int wm = wv >> 1, wn = wv & 1;
  const int cbase = lane & 15;
  const int kg = lane >> 4;

  f32x4 acc[2][8];
#pragma unroll
  for (int i = 0; i < 2; ++i)
#pragma unroll
    for (int j = 0; j < 8; ++j) acc[i][j] = {0.f, 0.f, 0.f, 0.f};

  const int arow = tid >> 2;
  const int acg = tid & 3;
  const float* hrow = h + (size_t)srcl[arow] * HD;
  float* htrow = h_tild + (size_t)dstl[arow] * HD;

  for (int kc = 0; kc < 4; ++kc) {
    const int k0 = kc * 64;
    const float4* s4 = (const float4*)(hrow + k0 + acg * 16);
    float4 q0 = s4[0], q1 = s4[1], q2 = s4[2], q3 = s4[3];
    short8 p0, p1;
    p0[0] = f2bf(q0.x); p0[1] = f2bf(q0.y); p0[2] = f2bf(q0.z); p0[3] = f2bf(q0.w);
    p0[4] = f2bf(q1.x); p0[5] = f2bf(q1.y); p0[6] = f2bf(q1.z); p0[7] = f2bf(q1.w);
    p1[0] = f2bf(q2.x); p1[1] = f2bf(q2.y); p1[2] = f2bf(q2.z); p1[3] = f2bf(q2.w);
    p1[4] = f2bf(q3.x); p1[5] = f2bf(q3.y); p1[6] = f2bf(q3.z); p1[7] = f2bf(q3.w);
    short8* ap = (short8*)&Als[arow * F_AS + acg * 16];
    ap[0] = p0; ap[1] = p1;
    {
      float* hp = htrow + k0 + acg * 16;
      atomAddF(hp + 0, q0.x);  atomAddF(hp + 1, q0.y);
      atomAddF(hp + 2, q0.z);  atomAddF(hp + 3, q0.w);
      atomAddF(hp + 4, q1.x);  atomAddF(hp + 5, q1.y);
      atomAddF(hp + 6, q1.z);  atomAddF(hp + 7, q1.w);
      atomAddF(hp + 8, q2.x);  atomAddF(hp + 9, q2.y);
      atomAddF(hp + 10, q2.z); atomAddF(hp + 11, q2.w);
      atomAddF(hp + 12, q3.x); atomAddF(hp + 13, q3.y);
      atomAddF(hp + 14, q3.z); atomAddF(hp + 15, q3.w);
    }
#pragma unroll
    for (int i = 0; i < 8; ++i) {
      int f = tid + 256 * i;
      int row = f >> 3, ch = f & 7;
      short8 vb = *(const short8*)(Wfb + row * 256 + k0 + ch * 8);
      *(short8*)&Bls[row * F_BS + ch * 8] = vb;
    }
    __syncthreads();
#pragma unroll
    for (int ks = 0; ks < 2; ++ks) {
      short8 a0 = *(const short8*)&Als[(wm * 32 + cbase) * F_AS + ks * 32 + kg * 8];
      short8 a1 = *(const short8*)&Als[(wm * 32 + 16 + cbase) * F_AS + ks * 32 + kg * 8];
#pragma unroll
      for (int nt = 0; nt < 8; ++nt) {
        short8 b = *(const short8*)&Bls[(wn * 128 + nt * 16 + cbase) * F_BS + ks * 32 + kg * 8];
        acc[0][nt] = __builtin_amdgcn_mfma_f32_16x16x32_bf16(a0, b, acc[0][nt], 0, 0, 0);
        acc[1][nt] = __builtin_amdgcn_mfma_f32_16x16x32_bf16(a1, b, acc[1][nt], 0, 0, 0);
      }
    }
    __syncthreads();
  }
  const int rsub = kg * 4;
#pragma unroll
  for (int nt = 0; nt < 8; ++nt) {
    const int coln = wn * 128 + nt * 16 + cbase;
    const float bias = Ufb[coln];
#pragma unroll
    for (int mt = 0; mt < 2; ++mt) {
#pragma unroll
      for (int j = 0; j < 4; ++j) {
        const int el = wm * 32 + mt * 16 + rsub + j;
        const float fg = sigmoidf_(acc[mt][nt][j] + bias);
        const float cv = c[(size_t)srcl[el] * HD + coln];
        atomAddF(c_agg + (size_t)dstl[el] * HD + coln, fg * cv);
      }
    }
  }
}

#define I_AS 40
#define I_BS 40

__global__ __launch_bounds__(256) void iou_kernel(
    const float* __restrict__ x, const unsigned short* __restrict__ Wioub,
    const unsigned short* __restrict__ Uioub, const float* __restrict__ bperm,
    float* out) {
  __shared__ __align__(16) unsigned short Als[32 * I_AS];
  __shared__ __align__(16) unsigned short Bls[768 * I_BS];

  const int tid = threadIdx.x;
  const int lane = tid & 63;
  const int wv = tid >> 6;
  const int wm = wv >> 1, wn = wv & 1;
  const int cbase = lane & 15;
  const int kg = lane >> 4;
  const int r0 = blockIdx.x * 32;

  float* h_tild = out;
  float* c_agg = out + (size_t)NN * HD;

  f32x4 acc[24];
#pragma unroll
  for (int t = 0; t < 24; ++t) acc[t] = {0.f, 0.f, 0.f, 0.f};

  const int arow = tid >> 3;
  const int acg = tid & 7;

  for (int pass = 0; pass < 2; ++pass) {
    const float* As = pass ? h_tild : x;
    const unsigned short* Bs = pass ? Uioub : Wioub;
    for (int kc = 0; kc < 8; ++kc) {
      const int k0 = kc * 32;
      float4 q = *(const float4*)(As + (size_t)(r0 + arow) * HD + k0 + acg * 4);
      short4v p;
      p[0] = f2bf(q.x); p[1] = f2bf(q.y); p[2] = f2bf(q.z); p[3] = f2bf(q.w);
      *(short4v*)&Als[arow * I_AS + acg * 4] = p;
#pragma unroll
      for (int i = 0; i < 12; ++i) {
        int f = tid + 256 * i;
        int row = f >> 2, ch = f & 3;
        short8 vb = *(const short8*)(Bs + row * 256 + k0 + ch * 8);
        *(short8*)&Bls[row * I_BS + ch * 8] = vb;
      }
      __syncthreads();
      short8 a = *(const short8*)&Als[(wm * 16 + cbase) * I_AS + kg * 8];
#pragma unroll
      for (int tt = 0; tt < 24; ++tt) {
        short8 b = *(const short8*)&Bls[((wn * 24 + tt) * 16 + cbase) * I_BS + kg * 8];
        acc[tt] = __builtin_amdgcn_mfma_f32_16x16x32_bf16(a, b, acc[tt], 0, 0, 0);
      }
      __syncthreads();
    }
  }
  const int rsub = kg * 4;
#pragma unroll
  for (int t3 = 0; t3 < 8; ++t3) {
    const int T = wn * 24 + 3 * t3;
    const float bi = bperm[(T + 0) * 16 + cbase];
    const float bo = bperm[(T + 1) * 16 + cbase];
    const float bu = bperm[(T + 2) * 16 + cbase];
    const int j = (wn * 8 + t3) * 16 + cbase;
#pragma unroll
    for (int jr = 0; jr < 4; ++jr) {
      const int r = r0 + wm * 16 + rsub + jr;
      const size_t idx = (size_t)r * HD + j;
      const float iv = sigmoidf_(acc[3 * t3 + 0][jr] + bi);
      const float ov = sigmoidf_(acc[3 * t3 + 1][jr] + bo);
      const float uv = tanhf_(acc[3 * t3 + 2][jr] + bu);
      const float cn = iv * uv + c_agg[idx];
      out[idx] = ov * tanhf_(cn);
      c_agg[idx] = cn;
    }
  }
}

extern "C" void kernel_launch(void* const* d_in, const int* in_sizes, int n_in,
                              void* d_out, int out_size, void* d_ws, size_t ws_size,
                              hipStream_t stream) {
  const float* x    = (const float*)d_in[0];
  const float* h    = (const float*)d_in[1];
  const float* c    = (const float*)d_in[2];
  const float* Wiou = (const float*)d_in[3];
  const float* Uiou = (const float*)d_in[4];
  const float* biou = (const float*)d_in[5];
  const float* Ufw  = (const float*)d_in[6];
  const float* Ufb  = (const float*)d_in[7];
  const int* esrc   = (const int*)d_in[8];
  const int* edst   = (const int*)d_in[9];
  float* out = (float*)d_out;

  char* ws = (char*)d_ws;
  unsigned short* Wfb   = (unsigned short*)(ws + OFF_WFB);
  unsigned short* Bp    = (unsigned short*)(ws + OFF_BP);
  float* bperm          = (float*)(ws + OFF_BPERM);

  if (ws_size >= WS_NEED) {
    int* rpp  = (int*)(ws + OFF_ROWPTR);
    int* nxt  = (int*)(ws + OFF_NEXT);
    int* slot = (int*)(ws + OFF_SLOT);
    int* psrc = (int*)(ws + OFF_PSRC);
    int* bsum = (int*)(ws + OFF_BSUM);
    char* zpage = ws + OFF_ZERO;
    unsigned short* fcb = (unsigned short*)(ws + OFF_FC);

    (void)hipMemsetAsync(nxt, 0, (size_t)NN * sizeof(int), stream);
    (void)hipMemsetAsync(zpage, 0, 1024, stream);
    prep_kernel<<<1795, 256, 0, stream>>>(Ufw, Wiou, Uiou, biou, Wfb, Bp, bperm);
    hist_kernel<<<(NE + 255) / 256, 256, 0, stream>>>(edst, nxt);
    scan_part<<<(NN + 1023) / 1024, 256, 0, stream>>>(nxt, rpp, bsum);
    scan_top<<<1, 256, 0, stream>>>(bsum, rpp, (NN + 1023) / 1024);
    scan_add<<<(NN + 1023) / 1024, 256, 0, stream>>>(rpp, bsum, nxt);
    scatter_kernel<<<(NE + 255) / 256, 256, 0, stream>>>(esrc, edst, nxt, slot, psrc);
    edge_fc_kernel<<<NE / 64, 256, 0, stream>>>(h, c, Wfb, Ufb, esrc, slot, fcb);
    gather_kernel<<<NN / 32, 256, 0, stream>>>(h, rpp, psrc, fcb, out + (size_t)NN * HD);
    const int rgrps = (NN + 127) / 128;
    if (ws_size >= WS_NEED2) {
      unsigned short* xb = (unsigned short*)(ws + OFF_XB);
      xcvt_kernel<<<(int)(((size_t)NN * HD / 8 + 255) / 256), 256, 0, stream>>>(x, xb);
      iou_gemm6_kernel<<<rgrps * 8, 256, 0, stream>>>(xb, Bp, bperm, rpp, fcb, zpage, out);
    } else {
      iou_gemm5_kernel<<<rgrps * 8, 256, 0, stream>>>(x, Bp, bperm, rpp, fcb, zpage, out);
    }
  } else {
    // fallback: R1 scatter-atomic path (row-major permuted weights in BP region)
    unsigned short* Wioub = (unsigned short*)(ws + OFF_BP);
    unsigned short* Uioub = (unsigned short*)(ws + OFF_BP + 393216);
    (void)hipMemsetAsync(d_out, 0, (size_t)out_size * sizeof(float), stream);
    prep_fb_kernel<<<1795, 256, 0, stream>>>(Ufw, Wiou, Uiou, biou, Wfb, Wioub, Uioub, bperm);
    edge_kernel<<<NE / 64, 256, 0, stream>>>(h, c, Wfb, Ufb, esrc, edst,
                                             out, out + (size_t)NN * HD);
    iou_kernel<<<NN / 32, 256, 0, stream>>>(x, Wioub, Uioub, bperm, out);
  }
}